// Round 1
// baseline (668.026 us; speedup 1.0000x reference)
//
#include <hip/hip_runtime.h>
#include <hip/hip_bf16.h>

// MoChA: monotonic chunkwise attention, fp32 throughout (round 1: correctness).
// B=8, QLEN=128, KLEN=1024, D=512, HM=HC=4, dk=128, NH=16, dv=32, CHUNK=4.

#define NEG_INF (-3.402823466e38f)
#define EPS_MOCHA 1e-6f
#define INV_SCALE 0.04419417382415922f  // 1/sqrt(512)

// ---------------------------------------------------------------------------
// Generic projection GEMM: C = A[M,512] @ W[512,512] + bias, up to 3 weight
// groups selected by blockIdx.y>>2 (each group has 4 column tiles of 128).
// Block: 256 threads, tile 128x128, BK=16, 8x8 microtile.
// ---------------------------------------------------------------------------
__global__ __launch_bounds__(256) void proj_gemm(
    const float* __restrict__ A,
    const float* __restrict__ W0, const float* __restrict__ b0, float* __restrict__ C0,
    const float* __restrict__ W1, const float* __restrict__ b1, float* __restrict__ C1,
    const float* __restrict__ W2, const float* __restrict__ b2, float* __restrict__ C2)
{
    __shared__ float As[16][128];
    __shared__ float Bs[16][132];
    const int tid = threadIdx.x;
    const int g  = blockIdx.y >> 2;
    const int nt = blockIdx.y & 3;
    const float* W    = (g == 0) ? W0 : ((g == 1) ? W1 : W2);
    const float* bias = (g == 0) ? b0 : ((g == 1) ? b1 : b2);
    float*       C    = (g == 0) ? C0 : ((g == 1) ? C1 : C2);
    const int m0 = blockIdx.x * 128;
    const int n0 = nt * 128;
    const int ty = tid >> 4, tx = tid & 15;

    float acc[8][8];
#pragma unroll
    for (int i = 0; i < 8; ++i)
#pragma unroll
        for (int j = 0; j < 8; ++j) acc[i][j] = 0.f;

    for (int k0 = 0; k0 < 512; k0 += 16) {
        // Stage A tile (128 rows x 16 k), transposed into As[k][m]
#pragma unroll
        for (int u = 0; u < 2; ++u) {
            int idx = tid * 2 + u;
            int row = idx >> 2, c = idx & 3;
            float4 v = *(const float4*)(A + (size_t)(m0 + row) * 512 + k0 + c * 4);
            As[c * 4 + 0][row] = v.x;
            As[c * 4 + 1][row] = v.y;
            As[c * 4 + 2][row] = v.z;
            As[c * 4 + 3][row] = v.w;
        }
        // Stage B tile (16 k x 128 n) directly
#pragma unroll
        for (int u = 0; u < 2; ++u) {
            int idx = tid * 2 + u;
            int kk = idx >> 5, c4 = idx & 31;
            float4 v = *(const float4*)(W + (size_t)(k0 + kk) * 512 + n0 + c4 * 4);
            *(float4*)&Bs[kk][c4 * 4] = v;
        }
        __syncthreads();
#pragma unroll
        for (int kk = 0; kk < 16; ++kk) {
            float a[8], bb[8];
            *(float4*)&a[0]  = *(const float4*)&As[kk][ty * 8];
            *(float4*)&a[4]  = *(const float4*)&As[kk][ty * 8 + 4];
            *(float4*)&bb[0] = *(const float4*)&Bs[kk][tx * 8];
            *(float4*)&bb[4] = *(const float4*)&Bs[kk][tx * 8 + 4];
#pragma unroll
            for (int i = 0; i < 8; ++i)
#pragma unroll
                for (int j = 0; j < 8; ++j)
                    acc[i][j] = fmaf(a[i], bb[j], acc[i][j]);
        }
        __syncthreads();
    }
    float bv[8];
#pragma unroll
    for (int j = 0; j < 8; ++j) bv[j] = bias[n0 + tx * 8 + j];
#pragma unroll
    for (int i = 0; i < 8; ++i) {
        float o[8];
#pragma unroll
        for (int j = 0; j < 8; ++j) o[j] = acc[i][j] + bv[j];
        float* Cp = C + (size_t)(m0 + ty * 8 + i) * 512 + n0 + tx * 8;
        *(float4*)Cp       = *(float4*)&o[0];
        *(float4*)(Cp + 4) = *(float4*)&o[4];
    }
}

// ---------------------------------------------------------------------------
// Energy: out[b,h,q,k] = dot_128(Qp[b,q,h], Kp[b,k,h]) / sqrt(512) (+ r), mask
// Block: 256 threads, tile [Q=128]x[KT=128], d-loop BK=16, 8x8 microtile.
// Grid: (k_tiles=8, h=4, b=8)
// ---------------------------------------------------------------------------
__global__ __launch_bounds__(256) void energy_kernel(
    const float* __restrict__ Qp, const float* __restrict__ Kp,
    const int* __restrict__ mask, float* __restrict__ out,
    const float* __restrict__ r_ptr, int use_r)
{
    __shared__ float Qs[16][128];
    __shared__ float Ks[16][132];
    const int tid = threadIdx.x;
    const int kt0 = blockIdx.x * 128;
    const int h = blockIdx.y;
    const int b = blockIdx.z;
    const int ty = tid >> 4, tx = tid & 15;

    const float* Qbase = Qp + (size_t)b * 128 * 512 + h * 128;
    const float* Kbase = Kp + (size_t)b * 1024 * 512 + h * 128;

    float acc[8][8];
#pragma unroll
    for (int i = 0; i < 8; ++i)
#pragma unroll
        for (int j = 0; j < 8; ++j) acc[i][j] = 0.f;

    for (int d0 = 0; d0 < 128; d0 += 16) {
#pragma unroll
        for (int u = 0; u < 2; ++u) {
            int idx = tid * 2 + u;
            int row = idx >> 2, c = idx & 3;
            float4 v = *(const float4*)(Qbase + (size_t)row * 512 + d0 + c * 4);
            Qs[c * 4 + 0][row] = v.x;
            Qs[c * 4 + 1][row] = v.y;
            Qs[c * 4 + 2][row] = v.z;
            Qs[c * 4 + 3][row] = v.w;
            float4 w = *(const float4*)(Kbase + (size_t)(kt0 + row) * 512 + d0 + c * 4);
            Ks[c * 4 + 0][row] = w.x;
            Ks[c * 4 + 1][row] = w.y;
            Ks[c * 4 + 2][row] = w.z;
            Ks[c * 4 + 3][row] = w.w;
        }
        __syncthreads();
#pragma unroll
        for (int kk = 0; kk < 16; ++kk) {
            float a[8], bb[8];
            *(float4*)&a[0]  = *(const float4*)&Qs[kk][ty * 8];
            *(float4*)&a[4]  = *(const float4*)&Qs[kk][ty * 8 + 4];
            *(float4*)&bb[0] = *(const float4*)&Ks[kk][tx * 8];
            *(float4*)&bb[4] = *(const float4*)&Ks[kk][tx * 8 + 4];
#pragma unroll
            for (int i = 0; i < 8; ++i)
#pragma unroll
                for (int j = 0; j < 8; ++j)
                    acc[i][j] = fmaf(a[i], bb[j], acc[i][j]);
        }
        __syncthreads();
    }

    const float rv = use_r ? r_ptr[0] : 0.f;
#pragma unroll
    for (int i = 0; i < 8; ++i) {
        int q = ty * 8 + i;
        const int* Mrow = mask + ((size_t)b * 128 + q) * 1024 + kt0 + tx * 8;
        int mm[8];
        *(int4*)&mm[0] = *(const int4*)Mrow;
        *(int4*)&mm[4] = *(const int4*)(Mrow + 4);
        float o[8];
#pragma unroll
        for (int j = 0; j < 8; ++j) {
            float v = acc[i][j] * INV_SCALE + rv;
            o[j] = mm[j] ? v : NEG_INF;
        }
        float* Orow = out + (((size_t)b * 4 + h) * 128 + q) * 1024 + kt0 + tx * 8;
        *(float4*)Orow       = *(float4*)&o[0];
        *(float4*)(Orow + 4) = *(float4*)&o[4];
    }
}

// ---------------------------------------------------------------------------
// Alpha recurrence. One block per (b,h) = 32 blocks, 256 threads, 4 k each.
// Per q: p=sigmoid(e); cp=exp(excl_cumsum(log(max(1-p,eps))));
//        aw = p*cp*cumsum(aw_prev/max(cp,eps))
// ---------------------------------------------------------------------------
__device__ __forceinline__ float block_scan_incl(float x, float* wpart)
{
    const int tid = threadIdx.x;
    const int lane = tid & 63, wid = tid >> 6;
#pragma unroll
    for (int off = 1; off < 64; off <<= 1) {
        float y = __shfl_up(x, off, 64);
        if (lane >= off) x += y;
    }
    if (lane == 63) wpart[wid] = x;
    __syncthreads();
    float add = 0.f;
#pragma unroll
    for (int w = 0; w < 3; ++w)
        if (w < wid) add += wpart[w];
    x += add;
    __syncthreads();
    return x;
}

__global__ __launch_bounds__(256) void alpha_kernel(
    const float* __restrict__ e_mono, float* __restrict__ alpha)
{
    __shared__ float wpart[4];
    const int bh = blockIdx.x;
    const int tid = threadIdx.x;
    const int k4 = tid * 4;
    const float* Ebase = e_mono + (size_t)bh * 128 * 1024;
    float* Abase = alpha + (size_t)bh * 128 * 1024;

    float aw[4];
    aw[0] = (tid == 0) ? 1.f : 0.f;
    aw[1] = aw[2] = aw[3] = 0.f;

    for (int q = 0; q < 128; ++q) {
        float4 ev = *(const float4*)(Ebase + (size_t)q * 1024 + k4);
        float e[4] = {ev.x, ev.y, ev.z, ev.w};
        float p[4], l[4];
#pragma unroll
        for (int i = 0; i < 4; ++i) {
            p[i] = 1.f / (1.f + expf(-e[i]));
            l[i] = logf(fmaxf(1.f - p[i], EPS_MOCHA));
        }
        float lsum = l[0] + l[1] + l[2] + l[3];
        float incl = block_scan_incl(lsum, wpart);
        float base = incl - lsum;  // exclusive prefix across threads
        float cl[4];
        cl[0] = base;
        cl[1] = base + l[0];
        cl[2] = cl[1] + l[1];
        cl[3] = cl[2] + l[2];
        float cp[4], t[4];
#pragma unroll
        for (int i = 0; i < 4; ++i) {
            cp[i] = expf(cl[i]);
            t[i] = aw[i] / fmaxf(cp[i], EPS_MOCHA);
        }
        float tsum = t[0] + t[1] + t[2] + t[3];
        float incl2 = block_scan_incl(tsum, wpart);
        float s = incl2 - tsum;  // exclusive prefix across threads
#pragma unroll
        for (int i = 0; i < 4; ++i) {
            s += t[i];           // inclusive within thread
            aw[i] = p[i] * cp[i] * s;
        }
        float4 av = make_float4(aw[0], aw[1], aw[2], aw[3]);
        *(float4*)(Abase + (size_t)q * 1024 + k4) = av;
    }
}

// ---------------------------------------------------------------------------
// Beta: per (b,hc,q) row: sexp = max(exp(e-rowmax),1e-5);
// denom = moving_sum(sexp, back=3, fwd=0);
// for hm: beta = sexp * moving_sum(alpha[hm]/denom, back=0, fwd=3)
// Grid: (q=128, hc=4, b=8). 256 threads, 4 k each.
// ---------------------------------------------------------------------------
__global__ __launch_bounds__(256) void beta_kernel(
    const float* __restrict__ e_chunk, const float* __restrict__ alpha,
    float* __restrict__ beta)
{
    __shared__ float sm[1024];
    __shared__ float tm[1028];
    __shared__ float red[4];
    const int q = blockIdx.x, hc = blockIdx.y, b = blockIdx.z;
    const int tid = threadIdx.x;
    const int lane = tid & 63, wid = tid >> 6;
    const int k4 = tid * 4;

    const float* Erow = e_chunk + (((size_t)b * 4 + hc) * 128 + q) * 1024;
    float4 ev = *(const float4*)(Erow + k4);
    float e[4] = {ev.x, ev.y, ev.z, ev.w};

    // block max
    float mx = fmaxf(fmaxf(e[0], e[1]), fmaxf(e[2], e[3]));
#pragma unroll
    for (int off = 32; off >= 1; off >>= 1)
        mx = fmaxf(mx, __shfl_xor(mx, off, 64));
    if (lane == 0) red[wid] = mx;
    if (tid < 4) tm[1024 + tid] = 0.f;  // zero pad for fwd window
    __syncthreads();
    mx = fmaxf(fmaxf(red[0], red[1]), fmaxf(red[2], red[3]));

    float sx[4];
#pragma unroll
    for (int i = 0; i < 4; ++i) {
        sx[i] = fmaxf(expf(e[i] - mx), 1e-5f);
        sm[k4 + i] = sx[i];
    }
    __syncthreads();

    float den[4];
#pragma unroll
    for (int i = 0; i < 4; ++i) {
        int k = k4 + i;
        float d = sm[k];
        if (k >= 1) d += sm[k - 1];
        if (k >= 2) d += sm[k - 2];
        if (k >= 3) d += sm[k - 3];
        den[i] = d;
    }

    for (int hm = 0; hm < 4; ++hm) {
        const float* Arow = alpha + (((size_t)b * 4 + hm) * 128 + q) * 1024;
        float4 av = *(const float4*)(Arow + k4);
        float t[4] = {av.x / den[0], av.y / den[1], av.z / den[2], av.w / den[3]};
#pragma unroll
        for (int i = 0; i < 4; ++i) tm[k4 + i] = t[i];
        __syncthreads();
        float o[4];
#pragma unroll
        for (int i = 0; i < 4; ++i) {
            int k = k4 + i;
            float ms = tm[k] + tm[k + 1] + tm[k + 2] + tm[k + 3];
            o[i] = sx[i] * ms;
        }
        float* Brow = beta + (((size_t)b * 16 + hm * 4 + hc) * 128 + q) * 1024;
        *(float4*)(Brow + k4) = make_float4(o[0], o[1], o[2], o[3]);
        __syncthreads();
    }
}

// ---------------------------------------------------------------------------
// Context: cv[b,q,h*32+d] = sum_k beta[b,h,q,k] * V[b,k,h*32+d]
// Grid: (qhalf=2, h=16, b=8). Block 256: ty 0..31 (2 q rows), tx 0..7 (4 d).
// ---------------------------------------------------------------------------
__global__ __launch_bounds__(256) void context_kernel(
    const float* __restrict__ beta, const float* __restrict__ V,
    float* __restrict__ cv)
{
    __shared__ float bS[32][64];
    __shared__ float vS[32][32];
    const int qh = blockIdx.x, h = blockIdx.y, b = blockIdx.z;
    const int tid = threadIdx.x;
    const int ty = tid >> 3, tx = tid & 7;
    const int q0 = qh * 64;

    const float* Bbase = beta + (((size_t)b * 16 + h) * 128 + q0) * 1024;
    const float* Vbase = V + (size_t)b * 1024 * 512 + h * 32;

    float acc[2][4];
#pragma unroll
    for (int i = 0; i < 2; ++i)
#pragma unroll
        for (int j = 0; j < 4; ++j) acc[i][j] = 0.f;

    for (int k0 = 0; k0 < 1024; k0 += 32) {
#pragma unroll
        for (int u = 0; u < 2; ++u) {
            int idx = tid * 2 + u;
            int row = idx >> 3, c = idx & 7;
            float4 v = *(const float4*)(Bbase + (size_t)row * 1024 + k0 + c * 4);
            bS[c * 4 + 0][row] = v.x;
            bS[c * 4 + 1][row] = v.y;
            bS[c * 4 + 2][row] = v.z;
            bS[c * 4 + 3][row] = v.w;
        }
        {
            int kk = tid >> 3, c = tid & 7;
            float4 v = *(const float4*)(Vbase + (size_t)(k0 + kk) * 512 + c * 4);
            *(float4*)&vS[kk][c * 4] = v;
        }
        __syncthreads();
#pragma unroll
        for (int kk = 0; kk < 32; ++kk) {
            float a0 = bS[kk][ty * 2], a1 = bS[kk][ty * 2 + 1];
            float bb[4];
            *(float4*)bb = *(const float4*)&vS[kk][tx * 4];
#pragma unroll
            for (int j = 0; j < 4; ++j) {
                acc[0][j] = fmaf(a0, bb[j], acc[0][j]);
                acc[1][j] = fmaf(a1, bb[j], acc[1][j]);
            }
        }
        __syncthreads();
    }
#pragma unroll
    for (int i = 0; i < 2; ++i) {
        float* Cp = cv + ((size_t)b * 128 + q0 + ty * 2 + i) * 512 + h * 32 + tx * 4;
        *(float4*)Cp = make_float4(acc[i][0], acc[i][1], acc[i][2], acc[i][3]);
    }
}

// ---------------------------------------------------------------------------
extern "C" void kernel_launch(void* const* d_in, const int* in_sizes, int n_in,
                              void* d_out, int out_size, void* d_ws, size_t ws_size,
                              hipStream_t stream)
{
    const float* key_x   = (const float*)d_in[0];
    const float* query_x = (const float*)d_in[1];
    const int*   mask    = (const int*)d_in[2];
    const float* wk_m = (const float*)d_in[3];
    const float* bk_m = (const float*)d_in[4];
    const float* wq_m = (const float*)d_in[5];
    const float* bq_m = (const float*)d_in[6];
    const float* r    = (const float*)d_in[7];
    const float* wk_c = (const float*)d_in[8];
    const float* bk_c = (const float*)d_in[9];
    const float* wq_c = (const float*)d_in[10];
    const float* bq_c = (const float*)d_in[11];
    const float* wv   = (const float*)d_in[12];
    const float* bv   = (const float*)d_in[13];
    const float* wo   = (const float*)d_in[14];
    const float* bo   = (const float*)d_in[15];
    float* out = (float*)d_out;

    float* ws = (float*)d_ws;
    const size_t MEG = 1024 * 1024;
    // Workspace layout (floats). beta (16M) overlays Km/Kc/Qm/Qc/e_mono,
    // which are all dead by the time beta_kernel runs. Peak = 28.5M floats.
    float* Km      = ws;                       // 4M
    float* Kc      = ws + 4 * MEG;             // 4M
    float* Qm      = ws + 8 * MEG;             // 0.5M
    float* Qc      = ws + 8 * MEG + 512 * 1024;// 0.5M
    float* e_mono  = ws + 9 * MEG;             // 4M
    float* beta    = ws;                       // 16M (overlay)
    float* V       = ws + 16 * MEG;            // 4M
    float* e_chunk = ws + 20 * MEG;            // 4M
    float* alpha   = ws + 24 * MEG;            // 4M
    float* cv      = ws + 28 * MEG;            // 0.5M

    // 1) key-side projections: Km, Kc, V  (M=8192)
    proj_gemm<<<dim3(64, 12), 256, 0, stream>>>(
        key_x, wk_m, bk_m, Km, wk_c, bk_c, Kc, wv, bv, V);
    // 2) query-side projections: Qm, Qc  (M=1024)
    proj_gemm<<<dim3(8, 8), 256, 0, stream>>>(
        query_x, wq_m, bq_m, Qm, wq_c, bq_c, Qc, wq_c, bq_c, Qc);
    // 3) energies
    energy_kernel<<<dim3(8, 4, 8), 256, 0, stream>>>(Qm, Km, mask, e_mono, r, 1);
    energy_kernel<<<dim3(8, 4, 8), 256, 0, stream>>>(Qc, Kc, mask, e_chunk, r, 0);
    // 4) monotonic alpha (recurrence over q)
    alpha_kernel<<<dim3(32), 256, 0, stream>>>(e_mono, alpha);
    // 5) chunkwise beta
    beta_kernel<<<dim3(128, 4, 8), 256, 0, stream>>>(e_chunk, alpha, beta);
    // 6) context vectors
    context_kernel<<<dim3(2, 16, 8), 256, 0, stream>>>(beta, V, cv);
    // 7) output projection (M=1024)
    proj_gemm<<<dim3(8, 4), 256, 0, stream>>>(
        cv, wo, bo, out, wo, bo, out, wo, bo, out);
}

// Round 3
// 599.734 us; speedup vs baseline: 1.1139x; 1.1139x over previous
//
#include <hip/hip_runtime.h>
#include <hip/hip_bf16.h>

// MoChA: monotonic chunkwise attention, fp32. Round 3: fix invcp workspace
// overlap (R2 bug: invcp@13M..17M clobbered V@16M). invcp now lives over dead
// Km region (0..4M). Alpha split + beta swizzle otherwise unchanged from R2.
// B=8, QLEN=128, KLEN=1024, D=512, HM=HC=4, dk=128, NH=16, dv=32, CHUNK=4.

#define NEG_INF (-3.402823466e38f)
#define EPS_MOCHA 1e-6f
#define INV_SCALE 0.04419417382415922f  // 1/sqrt(512)

// ---------------------------------------------------------------------------
// Generic projection GEMM: C = A[M,512] @ W[512,512] + bias, up to 3 weight
// groups selected by blockIdx.y>>2 (each group has 4 column tiles of 128).
// Block: 256 threads, tile 128x128, BK=16, 8x8 microtile.
// ---------------------------------------------------------------------------
__global__ __launch_bounds__(256) void proj_gemm(
    const float* __restrict__ A,
    const float* __restrict__ W0, const float* __restrict__ b0, float* __restrict__ C0,
    const float* __restrict__ W1, const float* __restrict__ b1, float* __restrict__ C1,
    const float* __restrict__ W2, const float* __restrict__ b2, float* __restrict__ C2)
{
    __shared__ float As[16][128];
    __shared__ float Bs[16][132];
    const int tid = threadIdx.x;
    const int g  = blockIdx.y >> 2;
    const int nt = blockIdx.y & 3;
    const float* W    = (g == 0) ? W0 : ((g == 1) ? W1 : W2);
    const float* bias = (g == 0) ? b0 : ((g == 1) ? b1 : b2);
    float*       C    = (g == 0) ? C0 : ((g == 1) ? C1 : C2);
    const int m0 = blockIdx.x * 128;
    const int n0 = nt * 128;
    const int ty = tid >> 4, tx = tid & 15;

    float acc[8][8];
#pragma unroll
    for (int i = 0; i < 8; ++i)
#pragma unroll
        for (int j = 0; j < 8; ++j) acc[i][j] = 0.f;

    for (int k0 = 0; k0 < 512; k0 += 16) {
#pragma unroll
        for (int u = 0; u < 2; ++u) {
            int idx = tid * 2 + u;
            int row = idx >> 2, c = idx & 3;
            float4 v = *(const float4*)(A + (size_t)(m0 + row) * 512 + k0 + c * 4);
            As[c * 4 + 0][row] = v.x;
            As[c * 4 + 1][row] = v.y;
            As[c * 4 + 2][row] = v.z;
            As[c * 4 + 3][row] = v.w;
        }
#pragma unroll
        for (int u = 0; u < 2; ++u) {
            int idx = tid * 2 + u;
            int kk = idx >> 5, c4 = idx & 31;
            float4 v = *(const float4*)(W + (size_t)(k0 + kk) * 512 + n0 + c4 * 4);
            *(float4*)&Bs[kk][c4 * 4] = v;
        }
        __syncthreads();
#pragma unroll
        for (int kk = 0; kk < 16; ++kk) {
            float a[8], bb[8];
            *(float4*)&a[0]  = *(const float4*)&As[kk][ty * 8];
            *(float4*)&a[4]  = *(const float4*)&As[kk][ty * 8 + 4];
            *(float4*)&bb[0] = *(const float4*)&Bs[kk][tx * 8];
            *(float4*)&bb[4] = *(const float4*)&Bs[kk][tx * 8 + 4];
#pragma unroll
            for (int i = 0; i < 8; ++i)
#pragma unroll
                for (int j = 0; j < 8; ++j)
                    acc[i][j] = fmaf(a[i], bb[j], acc[i][j]);
        }
        __syncthreads();
    }
    float bv[8];
#pragma unroll
    for (int j = 0; j < 8; ++j) bv[j] = bias[n0 + tx * 8 + j];
#pragma unroll
    for (int i = 0; i < 8; ++i) {
        float o[8];
#pragma unroll
        for (int j = 0; j < 8; ++j) o[j] = acc[i][j] + bv[j];
        float* Cp = C + (size_t)(m0 + ty * 8 + i) * 512 + n0 + tx * 8;
        *(float4*)Cp       = *(float4*)&o[0];
        *(float4*)(Cp + 4) = *(float4*)&o[4];
    }
}

// ---------------------------------------------------------------------------
// Energy: out[b,h,q,k] = dot_128(Qp[b,q,h], Kp[b,k,h]) / sqrt(512) (+ r), mask
// ---------------------------------------------------------------------------
__global__ __launch_bounds__(256) void energy_kernel(
    const float* __restrict__ Qp, const float* __restrict__ Kp,
    const int* __restrict__ mask, float* __restrict__ out,
    const float* __restrict__ r_ptr, int use_r)
{
    __shared__ float Qs[16][128];
    __shared__ float Ks[16][132];
    const int tid = threadIdx.x;
    const int kt0 = blockIdx.x * 128;
    const int h = blockIdx.y;
    const int b = blockIdx.z;
    const int ty = tid >> 4, tx = tid & 15;

    const float* Qbase = Qp + (size_t)b * 128 * 512 + h * 128;
    const float* Kbase = Kp + (size_t)b * 1024 * 512 + h * 128;

    float acc[8][8];
#pragma unroll
    for (int i = 0; i < 8; ++i)
#pragma unroll
        for (int j = 0; j < 8; ++j) acc[i][j] = 0.f;

    for (int d0 = 0; d0 < 128; d0 += 16) {
#pragma unroll
        for (int u = 0; u < 2; ++u) {
            int idx = tid * 2 + u;
            int row = idx >> 2, c = idx & 3;
            float4 v = *(const float4*)(Qbase + (size_t)row * 512 + d0 + c * 4);
            Qs[c * 4 + 0][row] = v.x;
            Qs[c * 4 + 1][row] = v.y;
            Qs[c * 4 + 2][row] = v.z;
            Qs[c * 4 + 3][row] = v.w;
            float4 w = *(const float4*)(Kbase + (size_t)(kt0 + row) * 512 + d0 + c * 4);
            Ks[c * 4 + 0][row] = w.x;
            Ks[c * 4 + 1][row] = w.y;
            Ks[c * 4 + 2][row] = w.z;
            Ks[c * 4 + 3][row] = w.w;
        }
        __syncthreads();
#pragma unroll
        for (int kk = 0; kk < 16; ++kk) {
            float a[8], bb[8];
            *(float4*)&a[0]  = *(const float4*)&Qs[kk][ty * 8];
            *(float4*)&a[4]  = *(const float4*)&Qs[kk][ty * 8 + 4];
            *(float4*)&bb[0] = *(const float4*)&Ks[kk][tx * 8];
            *(float4*)&bb[4] = *(const float4*)&Ks[kk][tx * 8 + 4];
#pragma unroll
            for (int i = 0; i < 8; ++i)
#pragma unroll
                for (int j = 0; j < 8; ++j)
                    acc[i][j] = fmaf(a[i], bb[j], acc[i][j]);
        }
        __syncthreads();
    }

    const float rv = use_r ? r_ptr[0] : 0.f;
#pragma unroll
    for (int i = 0; i < 8; ++i) {
        int q = ty * 8 + i;
        const int* Mrow = mask + ((size_t)b * 128 + q) * 1024 + kt0 + tx * 8;
        int mm[8];
        *(int4*)&mm[0] = *(const int4*)Mrow;
        *(int4*)&mm[4] = *(const int4*)(Mrow + 4);
        float o[8];
#pragma unroll
        for (int j = 0; j < 8; ++j) {
            float v = acc[i][j] * INV_SCALE + rv;
            o[j] = mm[j] ? v : NEG_INF;
        }
        float* Orow = out + (((size_t)b * 4 + h) * 128 + q) * 1024 + kt0 + tx * 8;
        *(float4*)Orow       = *(float4*)&o[0];
        *(float4*)(Orow + 4) = *(float4*)&o[4];
    }
}

// ---------------------------------------------------------------------------
// alpha_pre: fully parallel part of the monotonic recurrence.
// For each (b,h,q) row (4096 rows, one wave each, 16 k per lane):
//   p = sigmoid(e); l = log(max(1-p, eps)); cl = exclusive_cumsum_k(l);
//   cp = exp(cl); pcp = p*cp (in-place over e_mono); invcp = 1/max(cp,eps).
// ---------------------------------------------------------------------------
__global__ __launch_bounds__(256) void alpha_pre(
    const float* __restrict__ e_mono, float* __restrict__ pcp,
    float* __restrict__ invcp)
{
    const int tid = threadIdx.x;
    const int lane = tid & 63;
    const int row = blockIdx.x * 4 + (tid >> 6);
    const float* E = e_mono + (size_t)row * 1024 + lane * 16;

    float e[16];
    *(float4*)&e[0]  = *(const float4*)(E);
    *(float4*)&e[4]  = *(const float4*)(E + 4);
    *(float4*)&e[8]  = *(const float4*)(E + 8);
    *(float4*)&e[12] = *(const float4*)(E + 12);

    float p[16], l[16];
#pragma unroll
    for (int i = 0; i < 16; ++i) {
        p[i] = 1.f / (1.f + expf(-e[i]));
        l[i] = logf(fmaxf(1.f - p[i], EPS_MOCHA));
    }
    float incl[16];
    incl[0] = l[0];
#pragma unroll
    for (int i = 1; i < 16; ++i) incl[i] = incl[i - 1] + l[i];
    float total = incl[15];
    float x = total;
#pragma unroll
    for (int off = 1; off < 64; off <<= 1) {
        float y = __shfl_up(x, off, 64);
        if (lane >= off) x += y;
    }
    float base = x - total;  // exclusive across lanes

    float o1[16], o2[16];
#pragma unroll
    for (int i = 0; i < 16; ++i) {
        float cl = base + (i ? incl[i - 1] : 0.f);
        float cp = expf(cl);
        o1[i] = p[i] * cp;
        o2[i] = 1.f / fmaxf(cp, EPS_MOCHA);
    }
    float* P = pcp + (size_t)row * 1024 + lane * 16;
    float* I = invcp + (size_t)row * 1024 + lane * 16;
    *(float4*)(P)      = *(float4*)&o1[0];
    *(float4*)(P + 4)  = *(float4*)&o1[4];
    *(float4*)(P + 8)  = *(float4*)&o1[8];
    *(float4*)(P + 12) = *(float4*)&o1[12];
    *(float4*)(I)      = *(float4*)&o2[0];
    *(float4*)(I + 4)  = *(float4*)&o2[4];
    *(float4*)(I + 8)  = *(float4*)&o2[8];
    *(float4*)(I + 12) = *(float4*)&o2[12];
}

// ---------------------------------------------------------------------------
// alpha_scan: the sequential part. One wave per (b,h); 16 k per lane; zero
// barriers. Per q: aw = pcp * inclusive_cumsum_k(aw_prev * invcp).
// ---------------------------------------------------------------------------
__global__ __launch_bounds__(64) void alpha_scan(
    const float* __restrict__ pcp, const float* __restrict__ invcp,
    float* __restrict__ alpha)
{
    const int lane = threadIdx.x;
    const int bh = blockIdx.x;
    const float* P = pcp + (size_t)bh * 128 * 1024 + lane * 16;
    const float* I = invcp + (size_t)bh * 128 * 1024 + lane * 16;
    float* A = alpha + (size_t)bh * 128 * 1024 + lane * 16;

    float aw[16];
#pragma unroll
    for (int i = 0; i < 16; ++i) aw[i] = 0.f;
    if (lane == 0) aw[0] = 1.f;

    for (int q = 0; q < 128; ++q) {
        float pc[16], ic[16];
        const float* Pq = P + (size_t)q * 1024;
        const float* Iq = I + (size_t)q * 1024;
        *(float4*)&pc[0]  = *(const float4*)(Pq);
        *(float4*)&pc[4]  = *(const float4*)(Pq + 4);
        *(float4*)&pc[8]  = *(const float4*)(Pq + 8);
        *(float4*)&pc[12] = *(const float4*)(Pq + 12);
        *(float4*)&ic[0]  = *(const float4*)(Iq);
        *(float4*)&ic[4]  = *(const float4*)(Iq + 4);
        *(float4*)&ic[8]  = *(const float4*)(Iq + 8);
        *(float4*)&ic[12] = *(const float4*)(Iq + 12);

        float incl[16];
        incl[0] = aw[0] * ic[0];
#pragma unroll
        for (int i = 1; i < 16; ++i) incl[i] = incl[i - 1] + aw[i] * ic[i];
        float total = incl[15];
        float x = total;
#pragma unroll
        for (int off = 1; off < 64; off <<= 1) {
            float y = __shfl_up(x, off, 64);
            if (lane >= off) x += y;
        }
        float base = x - total;  // exclusive across lanes
#pragma unroll
        for (int i = 0; i < 16; ++i) aw[i] = pc[i] * (base + incl[i]);

        float* Aq = A + (size_t)q * 1024;
        *(float4*)(Aq)      = *(float4*)&aw[0];
        *(float4*)(Aq + 4)  = *(float4*)&aw[4];
        *(float4*)(Aq + 8)  = *(float4*)&aw[8];
        *(float4*)(Aq + 12) = *(float4*)&aw[12];
    }
}

// ---------------------------------------------------------------------------
// Beta. LDS arrays swizzled (SW(k)=k+(k>>3)) so the stride-4 scalar window
// reads land <=2-way per bank (free) instead of 8-way.
// Grid: (q=128, hc=4, b=8). 256 threads, 4 k each.
// ---------------------------------------------------------------------------
#define SW(k) ((k) + ((k) >> 3))

__global__ __launch_bounds__(256) void beta_kernel(
    const float* __restrict__ e_chunk, const float* __restrict__ alpha,
    float* __restrict__ beta)
{
    __shared__ float sm[SW(1023) + 1];
    __shared__ float tm[SW(1027) + 1];
    __shared__ float red[4];
    const int q = blockIdx.x, hc = blockIdx.y, b = blockIdx.z;
    const int tid = threadIdx.x;
    const int lane = tid & 63, wid = tid >> 6;
    const int k4 = tid * 4;

    const float* Erow = e_chunk + (((size_t)b * 4 + hc) * 128 + q) * 1024;
    float4 ev = *(const float4*)(Erow + k4);
    float e[4] = {ev.x, ev.y, ev.z, ev.w};

    float mx = fmaxf(fmaxf(e[0], e[1]), fmaxf(e[2], e[3]));
#pragma unroll
    for (int off = 32; off >= 1; off >>= 1)
        mx = fmaxf(mx, __shfl_xor(mx, off, 64));
    if (lane == 0) red[wid] = mx;
    if (tid < 4) tm[SW(1024 + tid)] = 0.f;  // zero pad for fwd window
    __syncthreads();
    mx = fmaxf(fmaxf(red[0], red[1]), fmaxf(red[2], red[3]));

    float sx[4];
#pragma unroll
    for (int i = 0; i < 4; ++i) {
        sx[i] = fmaxf(expf(e[i] - mx), 1e-5f);
        sm[SW(k4 + i)] = sx[i];
    }
    __syncthreads();

    float den[4];
#pragma unroll
    for (int i = 0; i < 4; ++i) {
        int k = k4 + i;
        float d = sm[SW(k)];
        if (k >= 1) d += sm[SW(k - 1)];
        if (k >= 2) d += sm[SW(k - 2)];
        if (k >= 3) d += sm[SW(k - 3)];
        den[i] = d;
    }

    for (int hm = 0; hm < 4; ++hm) {
        const float* Arow = alpha + (((size_t)b * 4 + hm) * 128 + q) * 1024;
        float4 av = *(const float4*)(Arow + k4);
        float t[4] = {av.x / den[0], av.y / den[1], av.z / den[2], av.w / den[3]};
#pragma unroll
        for (int i = 0; i < 4; ++i) tm[SW(k4 + i)] = t[i];
        __syncthreads();
        float o[4];
#pragma unroll
        for (int i = 0; i < 4; ++i) {
            int k = k4 + i;
            float ms = tm[SW(k)] + tm[SW(k + 1)] + tm[SW(k + 2)] + tm[SW(k + 3)];
            o[i] = sx[i] * ms;
        }
        float* Brow = beta + (((size_t)b * 16 + hm * 4 + hc) * 128 + q) * 1024;
        *(float4*)(Brow + k4) = make_float4(o[0], o[1], o[2], o[3]);
        __syncthreads();
    }
}

// ---------------------------------------------------------------------------
// Context: cv[b,q,h*32+d] = sum_k beta[b,h,q,k] * V[b,k,h*32+d]
// ---------------------------------------------------------------------------
__global__ __launch_bounds__(256) void context_kernel(
    const float* __restrict__ beta, const float* __restrict__ V,
    float* __restrict__ cv)
{
    __shared__ float bS[32][64];
    __shared__ float vS[32][32];
    const int qh = blockIdx.x, h = blockIdx.y, b = blockIdx.z;
    const int tid = threadIdx.x;
    const int ty = tid >> 3, tx = tid & 7;
    const int q0 = qh * 64;

    const float* Bbase = beta + (((size_t)b * 16 + h) * 128 + q0) * 1024;
    const float* Vbase = V + (size_t)b * 1024 * 512 + h * 32;

    float acc[2][4];
#pragma unroll
    for (int i = 0; i < 2; ++i)
#pragma unroll
        for (int j = 0; j < 4; ++j) acc[i][j] = 0.f;

    for (int k0 = 0; k0 < 1024; k0 += 32) {
#pragma unroll
        for (int u = 0; u < 2; ++u) {
            int idx = tid * 2 + u;
            int row = idx >> 3, c = idx & 7;
            float4 v = *(const float4*)(Bbase + (size_t)row * 1024 + k0 + c * 4);
            bS[c * 4 + 0][row] = v.x;
            bS[c * 4 + 1][row] = v.y;
            bS[c * 4 + 2][row] = v.z;
            bS[c * 4 + 3][row] = v.w;
        }
        {
            int kk = tid >> 3, c = tid & 7;
            float4 v = *(const float4*)(Vbase + (size_t)(k0 + kk) * 512 + c * 4);
            *(float4*)&vS[kk][c * 4] = v;
        }
        __syncthreads();
#pragma unroll
        for (int kk = 0; kk < 32; ++kk) {
            float a0 = bS[kk][ty * 2], a1 = bS[kk][ty * 2 + 1];
            float bb[4];
            *(float4*)bb = *(const float4*)&vS[kk][tx * 4];
#pragma unroll
            for (int j = 0; j < 4; ++j) {
                acc[0][j] = fmaf(a0, bb[j], acc[0][j]);
                acc[1][j] = fmaf(a1, bb[j], acc[1][j]);
            }
        }
        __syncthreads();
    }
#pragma unroll
    for (int i = 0; i < 2; ++i) {
        float* Cp = cv + ((size_t)b * 128 + q0 + ty * 2 + i) * 512 + h * 32 + tx * 4;
        *(float4*)Cp = make_float4(acc[i][0], acc[i][1], acc[i][2], acc[i][3]);
    }
}

// ---------------------------------------------------------------------------
extern "C" void kernel_launch(void* const* d_in, const int* in_sizes, int n_in,
                              void* d_out, int out_size, void* d_ws, size_t ws_size,
                              hipStream_t stream)
{
    const float* key_x   = (const float*)d_in[0];
    const float* query_x = (const float*)d_in[1];
    const int*   mask    = (const int*)d_in[2];
    const float* wk_m = (const float*)d_in[3];
    const float* bk_m = (const float*)d_in[4];
    const float* wq_m = (const float*)d_in[5];
    const float* bq_m = (const float*)d_in[6];
    const float* r    = (const float*)d_in[7];
    const float* wk_c = (const float*)d_in[8];
    const float* bk_c = (const float*)d_in[9];
    const float* wq_c = (const float*)d_in[10];
    const float* bq_c = (const float*)d_in[11];
    const float* wv   = (const float*)d_in[12];
    const float* bv   = (const float*)d_in[13];
    const float* wo   = (const float*)d_in[14];
    const float* bo   = (const float*)d_in[15];
    float* out = (float*)d_out;

    float* ws = (float*)d_ws;
    const size_t MEG = 1024 * 1024;
    // Workspace layout (floats), with lifetime-based overlays:
    //   phase A (projections+energies): Km 0-4M, Kc 4-8M, Qm 8-8.5M,
    //     Qc 8.5-9M, e_mono 9-13M, V 16-20M, e_chunk 20-24M
    //   phase B (alpha): pcp = e_mono in-place (9-13M);
    //     invcp = 0-4M (over dead Km — Km dead after energy #1)
    //   phase C (beta/context): beta 0-16M (over Km/Kc/Qm/Qc/pcp/invcp, all
    //     dead after alpha_scan), alpha 24-28M, cv 28-28.5M. Peak = 28.5M.
    float* Km      = ws;                        // 4M
    float* Kc      = ws + 4 * MEG;              // 4M
    float* Qm      = ws + 8 * MEG;              // 0.5M
    float* Qc      = ws + 8 * MEG + 512 * 1024; // 0.5M
    float* e_mono  = ws + 9 * MEG;              // 4M
    float* pcp     = e_mono;                    // in-place overlay
    float* invcp   = ws;                        // 4M (over dead Km)
    float* beta    = ws;                        // 16M (overlay, after alpha)
    float* V       = ws + 16 * MEG;             // 4M
    float* e_chunk = ws + 20 * MEG;             // 4M
    float* alpha   = ws + 24 * MEG;             // 4M
    float* cv      = ws + 28 * MEG;             // 0.5M

    // 1) key-side projections: Km, Kc, V  (M=8192)
    proj_gemm<<<dim3(64, 12), 256, 0, stream>>>(
        key_x, wk_m, bk_m, Km, wk_c, bk_c, Kc, wv, bv, V);
    // 2) query-side projections: Qm, Qc  (M=1024)
    proj_gemm<<<dim3(8, 8), 256, 0, stream>>>(
        query_x, wq_m, bq_m, Qm, wq_c, bq_c, Qc, wq_c, bq_c, Qc);
    // 3) energies
    energy_kernel<<<dim3(8, 4, 8), 256, 0, stream>>>(Qm, Km, mask, e_mono, r, 1);
    energy_kernel<<<dim3(8, 4, 8), 256, 0, stream>>>(Qc, Kc, mask, e_chunk, r, 0);
    // 4) monotonic alpha: parallel precompute + barrier-free wave scan
    alpha_pre<<<dim3(1024), 256, 0, stream>>>(e_mono, pcp, invcp);
    alpha_scan<<<dim3(32), 64, 0, stream>>>(pcp, invcp, alpha);
    // 5) chunkwise beta
    beta_kernel<<<dim3(128, 4, 8), 256, 0, stream>>>(e_chunk, alpha, beta);
    // 6) context vectors
    context_kernel<<<dim3(2, 16, 8), 256, 0, stream>>>(beta, V, cv);
    // 7) output projection (M=1024)
    proj_gemm<<<dim3(8, 4), 256, 0, stream>>>(
        cv, wo, bo, out, wo, bo, out, wo, bo, out);
}

// Round 4
// 540.976 us; speedup vs baseline: 1.2349x; 1.1086x over previous
//
#include <hip/hip_runtime.h>
#include <hip/hip_bf16.h>

// MoChA fp32. Round 4: LDS bank-conflict fixes (j-split fragment layout,
// stride-1 B staging) + register prefetch pipelining in proj/energy/alpha_scan.
// B=8, QLEN=128, KLEN=1024, D=512, HM=HC=4, dk=128, NH=16, dv=32, CHUNK=4.

#define NEG_INF (-3.402823466e38f)
#define EPS_MOCHA 1e-6f
#define INV_SCALE 0.04419417382415922f  // 1/sqrt(512)

// ---------------------------------------------------------------------------
// Projection GEMM: C = A[M,512] @ W[512,512] + bias, 3 weight groups via
// blockIdx.y>>2. Block 256, tile 128x128, BK=16, 8x8 microtile (j-split:
// thread owns cols tx*4..+3 and 64+tx*4..+3 -> conflict-free b128 LDS reads).
// ---------------------------------------------------------------------------
__global__ __launch_bounds__(256) void proj_gemm(
    const float* __restrict__ A,
    const float* __restrict__ W0, const float* __restrict__ b0, float* __restrict__ C0,
    const float* __restrict__ W1, const float* __restrict__ b1, float* __restrict__ C1,
    const float* __restrict__ W2, const float* __restrict__ b2, float* __restrict__ C2)
{
    __shared__ float As[16][128];
    __shared__ float Bs[16][132];
    const int tid = threadIdx.x;
    const int g  = blockIdx.y >> 2;
    const int nt = blockIdx.y & 3;
    const float* W    = (g == 0) ? W0 : ((g == 1) ? W1 : W2);
    const float* bias = (g == 0) ? b0 : ((g == 1) ? b1 : b2);
    float*       C    = (g == 0) ? C0 : ((g == 1) ? C1 : C2);
    const int m0 = blockIdx.x * 128;
    const int n0 = nt * 128;
    const int ty = tid >> 4, tx = tid & 15;

    // A staging indices (transpose): idx = tid*2+u -> row=idx>>2, c=idx&3
    const int arow0 = (tid * 2) >> 2, ac0 = (tid * 2) & 3;
    const int arow1 = (tid * 2 + 1) >> 2, ac1 = (tid * 2 + 1) & 3;
    // B staging indices (stride-1): idx = u*256+tid -> kk=idx>>5, c4=idx&31
    const int bkk0 = tid >> 5, bc0 = tid & 31;
    const int bkk1 = (256 + tid) >> 5, bc1 = tid & 31;

    float acc[8][8];
#pragma unroll
    for (int i = 0; i < 8; ++i)
#pragma unroll
        for (int j = 0; j < 8; ++j) acc[i][j] = 0.f;

    float4 rA0, rA1, rB0, rB1;
    // prologue: load k0=0 tile
    rA0 = *(const float4*)(A + (size_t)(m0 + arow0) * 512 + ac0 * 4);
    rA1 = *(const float4*)(A + (size_t)(m0 + arow1) * 512 + ac1 * 4);
    rB0 = *(const float4*)(W + (size_t)bkk0 * 512 + n0 + bc0 * 4);
    rB1 = *(const float4*)(W + (size_t)bkk1 * 512 + n0 + bc1 * 4);

    for (int k0 = 0; k0 < 512; k0 += 16) {
        __syncthreads();  // previous compute done before overwrite
        As[ac0 * 4 + 0][arow0] = rA0.x;
        As[ac0 * 4 + 1][arow0] = rA0.y;
        As[ac0 * 4 + 2][arow0] = rA0.z;
        As[ac0 * 4 + 3][arow0] = rA0.w;
        As[ac1 * 4 + 0][arow1] = rA1.x;
        As[ac1 * 4 + 1][arow1] = rA1.y;
        As[ac1 * 4 + 2][arow1] = rA1.z;
        As[ac1 * 4 + 3][arow1] = rA1.w;
        *(float4*)&Bs[bkk0][bc0 * 4] = rB0;
        *(float4*)&Bs[bkk1][bc1 * 4] = rB1;
        __syncthreads();
        if (k0 + 16 < 512) {  // prefetch next tile; overlaps compute below
            rA0 = *(const float4*)(A + (size_t)(m0 + arow0) * 512 + k0 + 16 + ac0 * 4);
            rA1 = *(const float4*)(A + (size_t)(m0 + arow1) * 512 + k0 + 16 + ac1 * 4);
            rB0 = *(const float4*)(W + (size_t)(k0 + 16 + bkk0) * 512 + n0 + bc0 * 4);
            rB1 = *(const float4*)(W + (size_t)(k0 + 16 + bkk1) * 512 + n0 + bc1 * 4);
        }
#pragma unroll
        for (int kk = 0; kk < 16; ++kk) {
            float a[8], bb[8];
            *(float4*)&a[0]  = *(const float4*)&As[kk][ty * 8];
            *(float4*)&a[4]  = *(const float4*)&As[kk][ty * 8 + 4];
            *(float4*)&bb[0] = *(const float4*)&Bs[kk][tx * 4];
            *(float4*)&bb[4] = *(const float4*)&Bs[kk][64 + tx * 4];
#pragma unroll
            for (int i = 0; i < 8; ++i)
#pragma unroll
                for (int j = 0; j < 8; ++j)
                    acc[i][j] = fmaf(a[i], bb[j], acc[i][j]);
        }
    }
    float bv[8];
#pragma unroll
    for (int j = 0; j < 4; ++j) {
        bv[j]     = bias[n0 + tx * 4 + j];
        bv[4 + j] = bias[n0 + 64 + tx * 4 + j];
    }
#pragma unroll
    for (int i = 0; i < 8; ++i) {
        float o[8];
#pragma unroll
        for (int j = 0; j < 8; ++j) o[j] = acc[i][j] + bv[j];
        float* Cp = C + (size_t)(m0 + ty * 8 + i) * 512 + n0;
        *(float4*)(Cp + tx * 4)      = *(float4*)&o[0];
        *(float4*)(Cp + 64 + tx * 4) = *(float4*)&o[4];
    }
}

// ---------------------------------------------------------------------------
// Energy: out[b,h,q,k] = dot_128(Qp[b,q,h], Kp[b,k,h]) / sqrt(512) (+ r), mask
// Same j-split + prefetch structure. Grid: (k_tiles=8, h=4, b=8).
// ---------------------------------------------------------------------------
__global__ __launch_bounds__(256) void energy_kernel(
    const float* __restrict__ Qp, const float* __restrict__ Kp,
    const int* __restrict__ mask, float* __restrict__ out,
    const float* __restrict__ r_ptr, int use_r)
{
    __shared__ float Qs[16][128];
    __shared__ float Ks[16][132];
    const int tid = threadIdx.x;
    const int kt0 = blockIdx.x * 128;
    const int h = blockIdx.y;
    const int b = blockIdx.z;
    const int ty = tid >> 4, tx = tid & 15;

    const float* Qbase = Qp + (size_t)b * 128 * 512 + h * 128;
    const float* Kbase = Kp + (size_t)b * 1024 * 512 + h * 128;

    const int row0 = (tid * 2) >> 2, c0 = (tid * 2) & 3;
    const int row1 = (tid * 2 + 1) >> 2, c1 = (tid * 2 + 1) & 3;

    float acc[8][8];
#pragma unroll
    for (int i = 0; i < 8; ++i)
#pragma unroll
        for (int j = 0; j < 8; ++j) acc[i][j] = 0.f;

    float4 rQ0, rQ1, rK0, rK1;
    rQ0 = *(const float4*)(Qbase + (size_t)row0 * 512 + c0 * 4);
    rQ1 = *(const float4*)(Qbase + (size_t)row1 * 512 + c1 * 4);
    rK0 = *(const float4*)(Kbase + (size_t)(kt0 + row0) * 512 + c0 * 4);
    rK1 = *(const float4*)(Kbase + (size_t)(kt0 + row1) * 512 + c1 * 4);

    for (int d0 = 0; d0 < 128; d0 += 16) {
        __syncthreads();
        Qs[c0 * 4 + 0][row0] = rQ0.x;
        Qs[c0 * 4 + 1][row0] = rQ0.y;
        Qs[c0 * 4 + 2][row0] = rQ0.z;
        Qs[c0 * 4 + 3][row0] = rQ0.w;
        Qs[c1 * 4 + 0][row1] = rQ1.x;
        Qs[c1 * 4 + 1][row1] = rQ1.y;
        Qs[c1 * 4 + 2][row1] = rQ1.z;
        Qs[c1 * 4 + 3][row1] = rQ1.w;
        Ks[c0 * 4 + 0][row0] = rK0.x;
        Ks[c0 * 4 + 1][row0] = rK0.y;
        Ks[c0 * 4 + 2][row0] = rK0.z;
        Ks[c0 * 4 + 3][row0] = rK0.w;
        Ks[c1 * 4 + 0][row1] = rK1.x;
        Ks[c1 * 4 + 1][row1] = rK1.y;
        Ks[c1 * 4 + 2][row1] = rK1.z;
        Ks[c1 * 4 + 3][row1] = rK1.w;
        __syncthreads();
        if (d0 + 16 < 128) {
            rQ0 = *(const float4*)(Qbase + (size_t)row0 * 512 + d0 + 16 + c0 * 4);
            rQ1 = *(const float4*)(Qbase + (size_t)row1 * 512 + d0 + 16 + c1 * 4);
            rK0 = *(const float4*)(Kbase + (size_t)(kt0 + row0) * 512 + d0 + 16 + c0 * 4);
            rK1 = *(const float4*)(Kbase + (size_t)(kt0 + row1) * 512 + d0 + 16 + c1 * 4);
        }
#pragma unroll
        for (int kk = 0; kk < 16; ++kk) {
            float a[8], bb[8];
            *(float4*)&a[0]  = *(const float4*)&Qs[kk][ty * 8];
            *(float4*)&a[4]  = *(const float4*)&Qs[kk][ty * 8 + 4];
            *(float4*)&bb[0] = *(const float4*)&Ks[kk][tx * 4];
            *(float4*)&bb[4] = *(const float4*)&Ks[kk][64 + tx * 4];
#pragma unroll
            for (int i = 0; i < 8; ++i)
#pragma unroll
                for (int j = 0; j < 8; ++j)
                    acc[i][j] = fmaf(a[i], bb[j], acc[i][j]);
        }
    }

    const float rv = use_r ? r_ptr[0] : 0.f;
#pragma unroll
    for (int i = 0; i < 8; ++i) {
        int q = ty * 8 + i;
        const int* Mrow = mask + ((size_t)b * 128 + q) * 1024 + kt0;
        int mm[8];
        *(int4*)&mm[0] = *(const int4*)(Mrow + tx * 4);
        *(int4*)&mm[4] = *(const int4*)(Mrow + 64 + tx * 4);
        float o[8];
#pragma unroll
        for (int j = 0; j < 8; ++j) {
            float v = acc[i][j] * INV_SCALE + rv;
            o[j] = mm[j] ? v : NEG_INF;
        }
        float* Orow = out + (((size_t)b * 4 + h) * 128 + q) * 1024 + kt0;
        *(float4*)(Orow + tx * 4)      = *(float4*)&o[0];
        *(float4*)(Orow + 64 + tx * 4) = *(float4*)&o[4];
    }
}

// ---------------------------------------------------------------------------
// alpha_pre: parallel part of the monotonic recurrence (one wave per row).
// ---------------------------------------------------------------------------
__global__ __launch_bounds__(256) void alpha_pre(
    const float* __restrict__ e_mono, float* __restrict__ pcp,
    float* __restrict__ invcp)
{
    const int tid = threadIdx.x;
    const int lane = tid & 63;
    const int row = blockIdx.x * 4 + (tid >> 6);
    const float* E = e_mono + (size_t)row * 1024 + lane * 16;

    float e[16];
    *(float4*)&e[0]  = *(const float4*)(E);
    *(float4*)&e[4]  = *(const float4*)(E + 4);
    *(float4*)&e[8]  = *(const float4*)(E + 8);
    *(float4*)&e[12] = *(const float4*)(E + 12);

    float p[16], l[16];
#pragma unroll
    for (int i = 0; i < 16; ++i) {
        p[i] = 1.f / (1.f + expf(-e[i]));
        l[i] = logf(fmaxf(1.f - p[i], EPS_MOCHA));
    }
    float incl[16];
    incl[0] = l[0];
#pragma unroll
    for (int i = 1; i < 16; ++i) incl[i] = incl[i - 1] + l[i];
    float total = incl[15];
    float x = total;
#pragma unroll
    for (int off = 1; off < 64; off <<= 1) {
        float y = __shfl_up(x, off, 64);
        if (lane >= off) x += y;
    }
    float base = x - total;  // exclusive across lanes

    float o1[16], o2[16];
#pragma unroll
    for (int i = 0; i < 16; ++i) {
        float cl = base + (i ? incl[i - 1] : 0.f);
        float cp = expf(cl);
        o1[i] = p[i] * cp;
        o2[i] = 1.f / fmaxf(cp, EPS_MOCHA);
    }
    float* P = pcp + (size_t)row * 1024 + lane * 16;
    float* I = invcp + (size_t)row * 1024 + lane * 16;
    *(float4*)(P)      = *(float4*)&o1[0];
    *(float4*)(P + 4)  = *(float4*)&o1[4];
    *(float4*)(P + 8)  = *(float4*)&o1[8];
    *(float4*)(P + 12) = *(float4*)&o1[12];
    *(float4*)(I)      = *(float4*)&o2[0];
    *(float4*)(I + 4)  = *(float4*)&o2[4];
    *(float4*)(I + 8)  = *(float4*)&o2[8];
    *(float4*)(I + 12) = *(float4*)&o2[12];
}

// ---------------------------------------------------------------------------
// alpha_scan: sequential over q, one wave per (b,h), zero barriers, 1-deep
// register prefetch so next-q loads overlap the serial scan chain.
// ---------------------------------------------------------------------------
__global__ __launch_bounds__(64) void alpha_scan(
    const float* __restrict__ pcp, const float* __restrict__ invcp,
    float* __restrict__ alpha)
{
    const int lane = threadIdx.x;
    const int bh = blockIdx.x;
    const float* P = pcp + (size_t)bh * 128 * 1024 + lane * 16;
    const float* I = invcp + (size_t)bh * 128 * 1024 + lane * 16;
    float* A = alpha + (size_t)bh * 128 * 1024 + lane * 16;

    float aw[16];
#pragma unroll
    for (int i = 0; i < 16; ++i) aw[i] = 0.f;
    if (lane == 0) aw[0] = 1.f;

    float pn[16], in_[16];
    *(float4*)&pn[0]   = *(const float4*)(P);
    *(float4*)&pn[4]   = *(const float4*)(P + 4);
    *(float4*)&pn[8]   = *(const float4*)(P + 8);
    *(float4*)&pn[12]  = *(const float4*)(P + 12);
    *(float4*)&in_[0]  = *(const float4*)(I);
    *(float4*)&in_[4]  = *(const float4*)(I + 4);
    *(float4*)&in_[8]  = *(const float4*)(I + 8);
    *(float4*)&in_[12] = *(const float4*)(I + 12);

    for (int q = 0; q < 128; ++q) {
        float pc[16], ic[16];
#pragma unroll
        for (int i = 0; i < 16; ++i) { pc[i] = pn[i]; ic[i] = in_[i]; }
        if (q < 127) {  // prefetch q+1; overlaps the scan chain below
            const float* Pq = P + (size_t)(q + 1) * 1024;
            const float* Iq = I + (size_t)(q + 1) * 1024;
            *(float4*)&pn[0]   = *(const float4*)(Pq);
            *(float4*)&pn[4]   = *(const float4*)(Pq + 4);
            *(float4*)&pn[8]   = *(const float4*)(Pq + 8);
            *(float4*)&pn[12]  = *(const float4*)(Pq + 12);
            *(float4*)&in_[0]  = *(const float4*)(Iq);
            *(float4*)&in_[4]  = *(const float4*)(Iq + 4);
            *(float4*)&in_[8]  = *(const float4*)(Iq + 8);
            *(float4*)&in_[12] = *(const float4*)(Iq + 12);
        }

        float incl[16];
        incl[0] = aw[0] * ic[0];
#pragma unroll
        for (int i = 1; i < 16; ++i) incl[i] = incl[i - 1] + aw[i] * ic[i];
        float total = incl[15];
        float x = total;
#pragma unroll
        for (int off = 1; off < 64; off <<= 1) {
            float y = __shfl_up(x, off, 64);
            if (lane >= off) x += y;
        }
        float base = x - total;  // exclusive across lanes
#pragma unroll
        for (int i = 0; i < 16; ++i) aw[i] = pc[i] * (base + incl[i]);

        float* Aq = A + (size_t)q * 1024;
        *(float4*)(Aq)      = *(float4*)&aw[0];
        *(float4*)(Aq + 4)  = *(float4*)&aw[4];
        *(float4*)(Aq + 8)  = *(float4*)&aw[8];
        *(float4*)(Aq + 12) = *(float4*)&aw[12];
    }
}

// ---------------------------------------------------------------------------
// Beta. LDS swizzle SW(k)=k+(k>>3). Grid: (q=128, hc=4, b=8).
// ---------------------------------------------------------------------------
#define SW(k) ((k) + ((k) >> 3))

__global__ __launch_bounds__(256) void beta_kernel(
    const float* __restrict__ e_chunk, const float* __restrict__ alpha,
    float* __restrict__ beta)
{
    __shared__ float sm[SW(1023) + 1];
    __shared__ float tm[SW(1027) + 1];
    __shared__ float red[4];
    const int q = blockIdx.x, hc = blockIdx.y, b = blockIdx.z;
    const int tid = threadIdx.x;
    const int lane = tid & 63, wid = tid >> 6;
    const int k4 = tid * 4;

    const float* Erow = e_chunk + (((size_t)b * 4 + hc) * 128 + q) * 1024;
    float4 ev = *(const float4*)(Erow + k4);
    float e[4] = {ev.x, ev.y, ev.z, ev.w};

    float mx = fmaxf(fmaxf(e[0], e[1]), fmaxf(e[2], e[3]));
#pragma unroll
    for (int off = 32; off >= 1; off >>= 1)
        mx = fmaxf(mx, __shfl_xor(mx, off, 64));
    if (lane == 0) red[wid] = mx;
    if (tid < 4) tm[SW(1024 + tid)] = 0.f;  // zero pad for fwd window
    __syncthreads();
    mx = fmaxf(fmaxf(red[0], red[1]), fmaxf(red[2], red[3]));

    float sx[4];
#pragma unroll
    for (int i = 0; i < 4; ++i) {
        sx[i] = fmaxf(expf(e[i] - mx), 1e-5f);
        sm[SW(k4 + i)] = sx[i];
    }
    __syncthreads();

    float den[4];
#pragma unroll
    for (int i = 0; i < 4; ++i) {
        int k = k4 + i;
        float d = sm[SW(k)];
        if (k >= 1) d += sm[SW(k - 1)];
        if (k >= 2) d += sm[SW(k - 2)];
        if (k >= 3) d += sm[SW(k - 3)];
        den[i] = d;
    }

    for (int hm = 0; hm < 4; ++hm) {
        const float* Arow = alpha + (((size_t)b * 4 + hm) * 128 + q) * 1024;
        float4 av = *(const float4*)(Arow + k4);
        float t[4] = {av.x / den[0], av.y / den[1], av.z / den[2], av.w / den[3]};
#pragma unroll
        for (int i = 0; i < 4; ++i) tm[SW(k4 + i)] = t[i];
        __syncthreads();
        float o[4];
#pragma unroll
        for (int i = 0; i < 4; ++i) {
            int k = k4 + i;
            float ms = tm[SW(k)] + tm[SW(k + 1)] + tm[SW(k + 2)] + tm[SW(k + 3)];
            o[i] = sx[i] * ms;
        }
        float* Brow = beta + (((size_t)b * 16 + hm * 4 + hc) * 128 + q) * 1024;
        *(float4*)(Brow + k4) = make_float4(o[0], o[1], o[2], o[3]);
        __syncthreads();
    }
}

// ---------------------------------------------------------------------------
// Context: cv[b,q,h*32+d] = sum_k beta[b,h,q,k] * V[b,k,h*32+d]
// ---------------------------------------------------------------------------
__global__ __launch_bounds__(256) void context_kernel(
    const float* __restrict__ beta, const float* __restrict__ V,
    float* __restrict__ cv)
{
    __shared__ float bS[32][64];
    __shared__ float vS[32][32];
    const int qh = blockIdx.x, h = blockIdx.y, b = blockIdx.z;
    const int tid = threadIdx.x;
    const int ty = tid >> 3, tx = tid & 7;
    const int q0 = qh * 64;

    const float* Bbase = beta + (((size_t)b * 16 + h) * 128 + q0) * 1024;
    const float* Vbase = V + (size_t)b * 1024 * 512 + h * 32;

    float acc[2][4];
#pragma unroll
    for (int i = 0; i < 2; ++i)
#pragma unroll
        for (int j = 0; j < 4; ++j) acc[i][j] = 0.f;

    for (int k0 = 0; k0 < 1024; k0 += 32) {
#pragma unroll
        for (int u = 0; u < 2; ++u) {
            int idx = tid * 2 + u;
            int row = idx >> 3, c = idx & 7;
            float4 v = *(const float4*)(Bbase + (size_t)row * 1024 + k0 + c * 4);
            bS[c * 4 + 0][row] = v.x;
            bS[c * 4 + 1][row] = v.y;
            bS[c * 4 + 2][row] = v.z;
            bS[c * 4 + 3][row] = v.w;
        }
        {
            int kk = tid >> 3, c = tid & 7;
            float4 v = *(const float4*)(Vbase + (size_t)(k0 + kk) * 512 + c * 4);
            *(float4*)&vS[kk][c * 4] = v;
        }
        __syncthreads();
#pragma unroll
        for (int kk = 0; kk < 32; ++kk) {
            float a0 = bS[kk][ty * 2], a1 = bS[kk][ty * 2 + 1];
            float bb[4];
            *(float4*)bb = *(const float4*)&vS[kk][tx * 4];
#pragma unroll
            for (int j = 0; j < 4; ++j) {
                acc[0][j] = fmaf(a0, bb[j], acc[0][j]);
                acc[1][j] = fmaf(a1, bb[j], acc[1][j]);
            }
        }
        __syncthreads();
    }
#pragma unroll
    for (int i = 0; i < 2; ++i) {
        float* Cp = cv + ((size_t)b * 128 + q0 + ty * 2 + i) * 512 + h * 32 + tx * 4;
        *(float4*)Cp = make_float4(acc[i][0], acc[i][1], acc[i][2], acc[i][3]);
    }
}

// ---------------------------------------------------------------------------
extern "C" void kernel_launch(void* const* d_in, const int* in_sizes, int n_in,
                              void* d_out, int out_size, void* d_ws, size_t ws_size,
                              hipStream_t stream)
{
    const float* key_x   = (const float*)d_in[0];
    const float* query_x = (const float*)d_in[1];
    const int*   mask    = (const int*)d_in[2];
    const float* wk_m = (const float*)d_in[3];
    const float* bk_m = (const float*)d_in[4];
    const float* wq_m = (const float*)d_in[5];
    const float* bq_m = (const float*)d_in[6];
    const float* r    = (const float*)d_in[7];
    const float* wk_c = (const float*)d_in[8];
    const float* bk_c = (const float*)d_in[9];
    const float* wq_c = (const float*)d_in[10];
    const float* bq_c = (const float*)d_in[11];
    const float* wv   = (const float*)d_in[12];
    const float* bv   = (const float*)d_in[13];
    const float* wo   = (const float*)d_in[14];
    const float* bo   = (const float*)d_in[15];
    float* out = (float*)d_out;

    float* ws = (float*)d_ws;
    const size_t MEG = 1024 * 1024;
    // Workspace (floats), lifetime overlays:
    //   phase A: Km 0-4M, Kc 4-8M, Qm 8-8.5M, Qc 8.5-9M, e_mono 9-13M,
    //            V 16-20M, e_chunk 20-24M
    //   phase B: pcp = e_mono (in-place); invcp = 0-4M (over dead Km)
    //   phase C: beta 0-16M (over dead Km/Kc/Qm/Qc/pcp/invcp),
    //            alpha 24-28M, cv 28-28.5M. Peak = 28.5M floats.
    float* Km      = ws;                        // 4M
    float* Kc      = ws + 4 * MEG;              // 4M
    float* Qm      = ws + 8 * MEG;              // 0.5M
    float* Qc      = ws + 8 * MEG + 512 * 1024; // 0.5M
    float* e_mono  = ws + 9 * MEG;              // 4M
    float* pcp     = e_mono;                    // in-place overlay
    float* invcp   = ws;                        // 4M (over dead Km)
    float* beta    = ws;                        // 16M (overlay, after alpha)
    float* V       = ws + 16 * MEG;             // 4M
    float* e_chunk = ws + 20 * MEG;             // 4M
    float* alpha   = ws + 24 * MEG;             // 4M
    float* cv      = ws + 28 * MEG;             // 0.5M

    // 1) key-side projections: Km, Kc, V  (M=8192)
    proj_gemm<<<dim3(64, 12), 256, 0, stream>>>(
        key_x, wk_m, bk_m, Km, wk_c, bk_c, Kc, wv, bv, V);
    // 2) query-side projections: Qm, Qc  (M=1024)
    proj_gemm<<<dim3(8, 8), 256, 0, stream>>>(
        query_x, wq_m, bq_m, Qm, wq_c, bq_c, Qc, wq_c, bq_c, Qc);
    // 3) energies
    energy_kernel<<<dim3(8, 4, 8), 256, 0, stream>>>(Qm, Km, mask, e_mono, r, 1);
    energy_kernel<<<dim3(8, 4, 8), 256, 0, stream>>>(Qc, Kc, mask, e_chunk, r, 0);
    // 4) monotonic alpha: parallel precompute + barrier-free wave scan
    alpha_pre<<<dim3(1024), 256, 0, stream>>>(e_mono, pcp, invcp);
    alpha_scan<<<dim3(32), 64, 0, stream>>>(pcp, invcp, alpha);
    // 5) chunkwise beta
    beta_kernel<<<dim3(128, 4, 8), 256, 0, stream>>>(e_chunk, alpha, beta);
    // 6) context vectors
    context_kernel<<<dim3(2, 16, 8), 256, 0, stream>>>(beta, V, cv);
    // 7) output projection (M=1024)
    proj_gemm<<<dim3(8, 4), 256, 0, stream>>>(
        cv, wo, bo, out, wo, bo, out, wo, bo, out);
}

// Round 5
// 388.179 us; speedup vs baseline: 1.7209x; 1.3936x over previous
//
#include <hip/hip_runtime.h>
#include <hip/hip_bf16.h>

// MoChA. Round 5: projections via fp16 MFMA (16x16x32, fp32 accumulate),
// LDS-free fragment loads from pre-packed fp16 operands.
// Energy/alpha/beta/context unchanged (fp32).
// B=8, QLEN=128, KLEN=1024, D=512, HM=HC=4, dk=128, NH=16, dv=32, CHUNK=4.

#define NEG_INF (-3.402823466e38f)
#define EPS_MOCHA 1e-6f
#define INV_SCALE 0.04419417382415922f  // 1/sqrt(512)

typedef _Float16 half8 __attribute__((ext_vector_type(8)));
typedef _Float16 half4v __attribute__((ext_vector_type(4)));
typedef float f32x4 __attribute__((ext_vector_type(4)));

// ---------------------------------------------------------------------------
// cvt: fp32 -> fp16, vectorized x4. Grid exactly n/4/256 blocks.
// ---------------------------------------------------------------------------
__global__ __launch_bounds__(256) void cvt_f32_f16(
    const float* __restrict__ in, _Float16* __restrict__ out)
{
    const size_t i = (size_t)blockIdx.x * 256 + threadIdx.x;
    float4 v = *(const float4*)(in + i * 4);
    half4v h = {(_Float16)v.x, (_Float16)v.y, (_Float16)v.z, (_Float16)v.w};
    *(half4v*)(out + i * 4) = h;
}

// ---------------------------------------------------------------------------
// pack_weights: Wt[n][k] = (fp16) W[k][n] for up to 5 weights (grid z).
// 64x64 tiles through LDS (pad 65 -> conflict-free column reads).
// ---------------------------------------------------------------------------
__global__ __launch_bounds__(256) void pack_weights(
    const float* __restrict__ Wa, const float* __restrict__ Wb,
    const float* __restrict__ Wc, const float* __restrict__ Wd,
    const float* __restrict__ We, _Float16* __restrict__ out)
{
    const int z = blockIdx.z;
    const float* W = (z == 0) ? Wa : (z == 1) ? Wb : (z == 2) ? Wc
                   : (z == 3) ? Wd : We;
    _Float16* O = out + (size_t)z * 512 * 512;
    const int n0 = blockIdx.x * 64, k0 = blockIdx.y * 64;
    __shared__ float T[64][65];
    const int t = threadIdx.x;
    const int rr = t >> 4, cc = (t & 15) * 4;
#pragma unroll
    for (int r = 0; r < 4; ++r) {
        int k = r * 16 + rr;
        float4 v = *(const float4*)(W + (size_t)(k0 + k) * 512 + n0 + cc);
        T[k][cc + 0] = v.x; T[k][cc + 1] = v.y;
        T[k][cc + 2] = v.z; T[k][cc + 3] = v.w;
    }
    __syncthreads();
    const int nn = t >> 2, kc = (t & 3) * 16;
    _Float16 tmp[16];
#pragma unroll
    for (int i = 0; i < 16; ++i) tmp[i] = (_Float16)T[kc + i][nn];
    _Float16* Op = O + (size_t)(n0 + nn) * 512 + k0 + kc;
    *(half8*)(Op)     = *(half8*)&tmp[0];
    *(half8*)(Op + 8) = *(half8*)&tmp[8];
}

// ---------------------------------------------------------------------------
// MFMA projection GEMM: C[m][n] = sum_k A16[m][k] * Wt[n][k] + bias.
// Block 256 = 4 waves (2x2), tile 128x128; wave tile 64x64 = 4x4 MFMA tiles.
// Fragments loaded directly from global (both operands k-contiguous; weights
// L2-resident). No LDS, no barriers. 1-deep register prefetch over K.
// Grid: (M/128, ngroups*4); group = blockIdx.y>>2 selects Wt/bias/C.
// ---------------------------------------------------------------------------
__device__ __forceinline__ void load_frags(
    const _Float16* Ap, const _Float16* Bp, int kk, half8 a[4], half8 b[4])
{
#pragma unroll
    for (int t = 0; t < 4; ++t) {
        a[t] = *(const half8*)(Ap + (size_t)t * 16 * 512 + kk);
        b[t] = *(const half8*)(Bp + (size_t)t * 16 * 512 + kk);
    }
}

__device__ __forceinline__ void mfma_step(half8 a[4], half8 b[4], f32x4 acc[4][4])
{
#pragma unroll
    for (int mt = 0; mt < 4; ++mt)
#pragma unroll
        for (int nt = 0; nt < 4; ++nt)
            acc[mt][nt] = __builtin_amdgcn_mfma_f32_16x16x32_f16(
                a[mt], b[nt], acc[mt][nt], 0, 0, 0);
}

__global__ __launch_bounds__(256) void mfma_proj(
    const _Float16* __restrict__ A16, const _Float16* __restrict__ Wt_base,
    const float* __restrict__ bias0, float* __restrict__ C0,
    const float* __restrict__ bias1, float* __restrict__ C1,
    const float* __restrict__ bias2, float* __restrict__ C2)
{
    const int tid = threadIdx.x;
    const int lane = tid & 63, wave = tid >> 6;
    const int wm = wave >> 1, wn = wave & 1;
    const int col = lane & 15, quad = lane >> 4;
    const int g = blockIdx.y >> 2, nt128 = blockIdx.y & 3;
    const _Float16* Wt = Wt_base + (size_t)g * 262144;
    const float* bias = (g == 0) ? bias0 : (g == 1) ? bias1 : bias2;
    float*       C    = (g == 0) ? C0    : (g == 1) ? C1    : C2;
    const int m0 = blockIdx.x * 128, n0 = nt128 * 128;

    const _Float16* Ap = A16 + (size_t)(m0 + wm * 64 + col) * 512 + quad * 8;
    const _Float16* Bp = Wt  + (size_t)(n0 + wn * 64 + col) * 512 + quad * 8;

    f32x4 acc[4][4];
#pragma unroll
    for (int mt = 0; mt < 4; ++mt)
#pragma unroll
        for (int nt = 0; nt < 4; ++nt) acc[mt][nt] = (f32x4)0.f;

    half8 af[4], bf[4], ag[4], bg[4];
    load_frags(Ap, Bp, 0, af, bf);
#pragma unroll
    for (int ks = 0; ks < 16; ks += 2) {
        load_frags(Ap, Bp, (ks + 1) * 32, ag, bg);
        mfma_step(af, bf, acc);
        if (ks + 2 < 16) load_frags(Ap, Bp, (ks + 2) * 32, af, bf);
        mfma_step(ag, bg, acc);
    }

    float bnt[4];
#pragma unroll
    for (int nt = 0; nt < 4; ++nt)
        bnt[nt] = bias[n0 + wn * 64 + nt * 16 + col];
#pragma unroll
    for (int mt = 0; mt < 4; ++mt) {
        const int rowb = m0 + wm * 64 + mt * 16 + quad * 4;
#pragma unroll
        for (int nt = 0; nt < 4; ++nt) {
            const int cc = n0 + wn * 64 + nt * 16 + col;
#pragma unroll
            for (int r = 0; r < 4; ++r)
                C[(size_t)(rowb + r) * 512 + cc] = acc[mt][nt][r] + bnt[nt];
        }
    }
}

// ---------------------------------------------------------------------------
// Energy (fp32, unchanged): out = dot_128(Qp,Kp)/sqrt(512) (+r), masked.
// ---------------------------------------------------------------------------
__global__ __launch_bounds__(256) void energy_kernel(
    const float* __restrict__ Qp, const float* __restrict__ Kp,
    const int* __restrict__ mask, float* __restrict__ out,
    const float* __restrict__ r_ptr, int use_r)
{
    __shared__ float Qs[16][128];
    __shared__ float Ks[16][132];
    const int tid = threadIdx.x;
    const int kt0 = blockIdx.x * 128;
    const int h = blockIdx.y;
    const int b = blockIdx.z;
    const int ty = tid >> 4, tx = tid & 15;

    const float* Qbase = Qp + (size_t)b * 128 * 512 + h * 128;
    const float* Kbase = Kp + (size_t)b * 1024 * 512 + h * 128;

    const int row0 = (tid * 2) >> 2, c0 = (tid * 2) & 3;
    const int row1 = (tid * 2 + 1) >> 2, c1 = (tid * 2 + 1) & 3;

    float acc[8][8];
#pragma unroll
    for (int i = 0; i < 8; ++i)
#pragma unroll
        for (int j = 0; j < 8; ++j) acc[i][j] = 0.f;

    float4 rQ0, rQ1, rK0, rK1;
    rQ0 = *(const float4*)(Qbase + (size_t)row0 * 512 + c0 * 4);
    rQ1 = *(const float4*)(Qbase + (size_t)row1 * 512 + c1 * 4);
    rK0 = *(const float4*)(Kbase + (size_t)(kt0 + row0) * 512 + c0 * 4);
    rK1 = *(const float4*)(Kbase + (size_t)(kt0 + row1) * 512 + c1 * 4);

    for (int d0 = 0; d0 < 128; d0 += 16) {
        __syncthreads();
        Qs[c0 * 4 + 0][row0] = rQ0.x;
        Qs[c0 * 4 + 1][row0] = rQ0.y;
        Qs[c0 * 4 + 2][row0] = rQ0.z;
        Qs[c0 * 4 + 3][row0] = rQ0.w;
        Qs[c1 * 4 + 0][row1] = rQ1.x;
        Qs[c1 * 4 + 1][row1] = rQ1.y;
        Qs[c1 * 4 + 2][row1] = rQ1.z;
        Qs[c1 * 4 + 3][row1] = rQ1.w;
        Ks[c0 * 4 + 0][row0] = rK0.x;
        Ks[c0 * 4 + 1][row0] = rK0.y;
        Ks[c0 * 4 + 2][row0] = rK0.z;
        Ks[c0 * 4 + 3][row0] = rK0.w;
        Ks[c1 * 4 + 0][row1] = rK1.x;
        Ks[c1 * 4 + 1][row1] = rK1.y;
        Ks[c1 * 4 + 2][row1] = rK1.z;
        Ks[c1 * 4 + 3][row1] = rK1.w;
        __syncthreads();
        if (d0 + 16 < 128) {
            rQ0 = *(const float4*)(Qbase + (size_t)row0 * 512 + d0 + 16 + c0 * 4);
            rQ1 = *(const float4*)(Qbase + (size_t)row1 * 512 + d0 + 16 + c1 * 4);
            rK0 = *(const float4*)(Kbase + (size_t)(kt0 + row0) * 512 + d0 + 16 + c0 * 4);
            rK1 = *(const float4*)(Kbase + (size_t)(kt0 + row1) * 512 + d0 + 16 + c1 * 4);
        }
#pragma unroll
        for (int kk = 0; kk < 16; ++kk) {
            float a[8], bb[8];
            *(float4*)&a[0]  = *(const float4*)&Qs[kk][ty * 8];
            *(float4*)&a[4]  = *(const float4*)&Qs[kk][ty * 8 + 4];
            *(float4*)&bb[0] = *(const float4*)&Ks[kk][tx * 4];
            *(float4*)&bb[4] = *(const float4*)&Ks[kk][64 + tx * 4];
#pragma unroll
            for (int i = 0; i < 8; ++i)
#pragma unroll
                for (int j = 0; j < 8; ++j)
                    acc[i][j] = fmaf(a[i], bb[j], acc[i][j]);
        }
    }

    const float rv = use_r ? r_ptr[0] : 0.f;
#pragma unroll
    for (int i = 0; i < 8; ++i) {
        int q = ty * 8 + i;
        const int* Mrow = mask + ((size_t)b * 128 + q) * 1024 + kt0;
        int mm[8];
        *(int4*)&mm[0] = *(const int4*)(Mrow + tx * 4);
        *(int4*)&mm[4] = *(const int4*)(Mrow + 64 + tx * 4);
        float o[8];
#pragma unroll
        for (int j = 0; j < 8; ++j) {
            float v = acc[i][j] * INV_SCALE + rv;
            o[j] = mm[j] ? v : NEG_INF;
        }
        float* Orow = out + (((size_t)b * 4 + h) * 128 + q) * 1024 + kt0;
        *(float4*)(Orow + tx * 4)      = *(float4*)&o[0];
        *(float4*)(Orow + 64 + tx * 4) = *(float4*)&o[4];
    }
}

// ---------------------------------------------------------------------------
// alpha_pre: parallel part of the monotonic recurrence (one wave per row).
// ---------------------------------------------------------------------------
__global__ __launch_bounds__(256) void alpha_pre(
    const float* __restrict__ e_mono, float* __restrict__ pcp,
    float* __restrict__ invcp)
{
    const int tid = threadIdx.x;
    const int lane = tid & 63;
    const int row = blockIdx.x * 4 + (tid >> 6);
    const float* E = e_mono + (size_t)row * 1024 + lane * 16;

    float e[16];
    *(float4*)&e[0]  = *(const float4*)(E);
    *(float4*)&e[4]  = *(const float4*)(E + 4);
    *(float4*)&e[8]  = *(const float4*)(E + 8);
    *(float4*)&e[12] = *(const float4*)(E + 12);

    float p[16], l[16];
#pragma unroll
    for (int i = 0; i < 16; ++i) {
        p[i] = 1.f / (1.f + expf(-e[i]));
        l[i] = logf(fmaxf(1.f - p[i], EPS_MOCHA));
    }
    float incl[16];
    incl[0] = l[0];
#pragma unroll
    for (int i = 1; i < 16; ++i) incl[i] = incl[i - 1] + l[i];
    float total = incl[15];
    float x = total;
#pragma unroll
    for (int off = 1; off < 64; off <<= 1) {
        float y = __shfl_up(x, off, 64);
        if (lane >= off) x += y;
    }
    float base = x - total;  // exclusive across lanes

    float o1[16], o2[16];
#pragma unroll
    for (int i = 0; i < 16; ++i) {
        float cl = base + (i ? incl[i - 1] : 0.f);
        float cp = expf(cl);
        o1[i] = p[i] * cp;
        o2[i] = 1.f / fmaxf(cp, EPS_MOCHA);
    }
    float* P = pcp + (size_t)row * 1024 + lane * 16;
    float* I = invcp + (size_t)row * 1024 + lane * 16;
    *(float4*)(P)      = *(float4*)&o1[0];
    *(float4*)(P + 4)  = *(float4*)&o1[4];
    *(float4*)(P + 8)  = *(float4*)&o1[8];
    *(float4*)(P + 12) = *(float4*)&o1[12];
    *(float4*)(I)      = *(float4*)&o2[0];
    *(float4*)(I + 4)  = *(float4*)&o2[4];
    *(float4*)(I + 8)  = *(float4*)&o2[8];
    *(float4*)(I + 12) = *(float4*)&o2[12];
}

// ---------------------------------------------------------------------------
// alpha_scan: sequential over q, one wave per (b,h), zero barriers, 1-deep
// register prefetch so next-q loads overlap the serial scan chain.
// ---------------------------------------------------------------------------
__global__ __launch_bounds__(64) void alpha_scan(
    const float* __restrict__ pcp, const float* __restrict__ invcp,
    float* __restrict__ alpha)
{
    const int lane = threadIdx.x;
    const int bh = blockIdx.x;
    const float* P = pcp + (size_t)bh * 128 * 1024 + lane * 16;
    const float* I = invcp + (size_t)bh * 128 * 1024 + lane * 16;
    float* A = alpha + (size_t)bh * 128 * 1024 + lane * 16;

    float aw[16];
#pragma unroll
    for (int i = 0; i < 16; ++i) aw[i] = 0.f;
    if (lane == 0) aw[0] = 1.f;

    float pn[16], in_[16];
    *(float4*)&pn[0]   = *(const float4*)(P);
    *(float4*)&pn[4]   = *(const float4*)(P + 4);
    *(float4*)&pn[8]   = *(const float4*)(P + 8);
    *(float4*)&pn[12]  = *(const float4*)(P + 12);
    *(float4*)&in_[0]  = *(const float4*)(I);
    *(float4*)&in_[4]  = *(const float4*)(I + 4);
    *(float4*)&in_[8]  = *(const float4*)(I + 8);
    *(float4*)&in_[12] = *(const float4*)(I + 12);

    for (int q = 0; q < 128; ++q) {
        float pc[16], ic[16];
#pragma unroll
        for (int i = 0; i < 16; ++i) { pc[i] = pn[i]; ic[i] = in_[i]; }
        if (q < 127) {
            const float* Pq = P + (size_t)(q + 1) * 1024;
            const float* Iq = I + (size_t)(q + 1) * 1024;
            *(float4*)&pn[0]   = *(const float4*)(Pq);
            *(float4*)&pn[4]   = *(const float4*)(Pq + 4);
            *(float4*)&pn[8]   = *(const float4*)(Pq + 8);
            *(float4*)&pn[12]  = *(const float4*)(Pq + 12);
            *(float4*)&in_[0]  = *(const float4*)(Iq);
            *(float4*)&in_[4]  = *(const float4*)(Iq + 4);
            *(float4*)&in_[8]  = *(const float4*)(Iq + 8);
            *(float4*)&in_[12] = *(const float4*)(Iq + 12);
        }

        float incl[16];
        incl[0] = aw[0] * ic[0];
#pragma unroll
        for (int i = 1; i < 16; ++i) incl[i] = incl[i - 1] + aw[i] * ic[i];
        float total = incl[15];
        float x = total;
#pragma unroll
        for (int off = 1; off < 64; off <<= 1) {
            float y = __shfl_up(x, off, 64);
            if (lane >= off) x += y;
        }
        float base = x - total;
#pragma unroll
        for (int i = 0; i < 16; ++i) aw[i] = pc[i] * (base + incl[i]);

        float* Aq = A + (size_t)q * 1024;
        *(float4*)(Aq)      = *(float4*)&aw[0];
        *(float4*)(Aq + 4)  = *(float4*)&aw[4];
        *(float4*)(Aq + 8)  = *(float4*)&aw[8];
        *(float4*)(Aq + 12) = *(float4*)&aw[12];
    }
}

// ---------------------------------------------------------------------------
// Beta. LDS swizzle SW(k)=k+(k>>3). Grid: (q=128, hc=4, b=8).
// ---------------------------------------------------------------------------
#define SW(k) ((k) + ((k) >> 3))

__global__ __launch_bounds__(256) void beta_kernel(
    const float* __restrict__ e_chunk, const float* __restrict__ alpha,
    float* __restrict__ beta)
{
    __shared__ float sm[SW(1023) + 1];
    __shared__ float tm[SW(1027) + 1];
    __shared__ float red[4];
    const int q = blockIdx.x, hc = blockIdx.y, b = blockIdx.z;
    const int tid = threadIdx.x;
    const int lane = tid & 63, wid = tid >> 6;
    const int k4 = tid * 4;

    const float* Erow = e_chunk + (((size_t)b * 4 + hc) * 128 + q) * 1024;
    float4 ev = *(const float4*)(Erow + k4);
    float e[4] = {ev.x, ev.y, ev.z, ev.w};

    float mx = fmaxf(fmaxf(e[0], e[1]), fmaxf(e[2], e[3]));
#pragma unroll
    for (int off = 32; off >= 1; off >>= 1)
        mx = fmaxf(mx, __shfl_xor(mx, off, 64));
    if (lane == 0) red[wid] = mx;
    if (tid < 4) tm[SW(1024 + tid)] = 0.f;
    __syncthreads();
    mx = fmaxf(fmaxf(red[0], red[1]), fmaxf(red[2], red[3]));

    float sx[4];
#pragma unroll
    for (int i = 0; i < 4; ++i) {
        sx[i] = fmaxf(expf(e[i] - mx), 1e-5f);
        sm[SW(k4 + i)] = sx[i];
    }
    __syncthreads();

    float den[4];
#pragma unroll
    for (int i = 0; i < 4; ++i) {
        int k = k4 + i;
        float d = sm[SW(k)];
        if (k >= 1) d += sm[SW(k - 1)];
        if (k >= 2) d += sm[SW(k - 2)];
        if (k >= 3) d += sm[SW(k - 3)];
        den[i] = d;
    }

    for (int hm = 0; hm < 4; ++hm) {
        const float* Arow = alpha + (((size_t)b * 4 + hm) * 128 + q) * 1024;
        float4 av = *(const float4*)(Arow + k4);
        float t[4] = {av.x / den[0], av.y / den[1], av.z / den[2], av.w / den[3]};
#pragma unroll
        for (int i = 0; i < 4; ++i) tm[SW(k4 + i)] = t[i];
        __syncthreads();
        float o[4];
#pragma unroll
        for (int i = 0; i < 4; ++i) {
            int k = k4 + i;
            float ms = tm[SW(k)] + tm[SW(k + 1)] + tm[SW(k + 2)] + tm[SW(k + 3)];
            o[i] = sx[i] * ms;
        }
        float* Brow = beta + (((size_t)b * 16 + hm * 4 + hc) * 128 + q) * 1024;
        *(float4*)(Brow + k4) = make_float4(o[0], o[1], o[2], o[3]);
        __syncthreads();
    }
}

// ---------------------------------------------------------------------------
// Context: cv[b,q,h*32+d] = sum_k beta[b,h,q,k] * V[b,k,h*32+d]
// ---------------------------------------------------------------------------
__global__ __launch_bounds__(256) void context_kernel(
    const float* __restrict__ beta, const float* __restrict__ V,
    float* __restrict__ cv)
{
    __shared__ float bS[32][64];
    __shared__ float vS[32][32];
    const int qh = blockIdx.x, h = blockIdx.y, b = blockIdx.z;
    const int tid = threadIdx.x;
    const int ty = tid >> 3, tx = tid & 7;
    const int q0 = qh * 64;

    const float* Bbase = beta + (((size_t)b * 16 + h) * 128 + q0) * 1024;
    const float* Vbase = V + (size_t)b * 1024 * 512 + h * 32;

    float acc[2][4];
#pragma unroll
    for (int i = 0; i < 2; ++i)
#pragma unroll
        for (int j = 0; j < 4; ++j) acc[i][j] = 0.f;

    for (int k0 = 0; k0 < 1024; k0 += 32) {
#pragma unroll
        for (int u = 0; u < 2; ++u) {
            int idx = tid * 2 + u;
            int row = idx >> 3, c = idx & 7;
            float4 v = *(const float4*)(Bbase + (size_t)row * 1024 + k0 + c * 4);
            bS[c * 4 + 0][row] = v.x;
            bS[c * 4 + 1][row] = v.y;
            bS[c * 4 + 2][row] = v.z;
            bS[c * 4 + 3][row] = v.w;
        }
        {
            int kk = tid >> 3, c = tid & 7;
            float4 v = *(const float4*)(Vbase + (size_t)(k0 + kk) * 512 + c * 4);
            *(float4*)&vS[kk][c * 4] = v;
        }
        __syncthreads();
#pragma unroll
        for (int kk = 0; kk < 32; ++kk) {
            float a0 = bS[kk][ty * 2], a1 = bS[kk][ty * 2 + 1];
            float bb[4];
            *(float4*)bb = *(const float4*)&vS[kk][tx * 4];
#pragma unroll
            for (int j = 0; j < 4; ++j) {
                acc[0][j] = fmaf(a0, bb[j], acc[0][j]);
                acc[1][j] = fmaf(a1, bb[j], acc[1][j]);
            }
        }
        __syncthreads();
    }
#pragma unroll
    for (int i = 0; i < 2; ++i) {
        float* Cp = cv + ((size_t)b * 128 + q0 + ty * 2 + i) * 512 + h * 32 + tx * 4;
        *(float4*)Cp = make_float4(acc[i][0], acc[i][1], acc[i][2], acc[i][3]);
    }
}

// ---------------------------------------------------------------------------
extern "C" void kernel_launch(void* const* d_in, const int* in_sizes, int n_in,
                              void* d_out, int out_size, void* d_ws, size_t ws_size,
                              hipStream_t stream)
{
    const float* key_x   = (const float*)d_in[0];
    const float* query_x = (const float*)d_in[1];
    const int*   mask    = (const int*)d_in[2];
    const float* wk_m = (const float*)d_in[3];
    const float* bk_m = (const float*)d_in[4];
    const float* wq_m = (const float*)d_in[5];
    const float* bq_m = (const float*)d_in[6];
    const float* r    = (const float*)d_in[7];
    const float* wk_c = (const float*)d_in[8];
    const float* bk_c = (const float*)d_in[9];
    const float* wq_c = (const float*)d_in[10];
    const float* bq_c = (const float*)d_in[11];
    const float* wv   = (const float*)d_in[12];
    const float* bv   = (const float*)d_in[13];
    const float* wo   = (const float*)d_in[14];
    const float* bo   = (const float*)d_in[15];
    float* out = (float*)d_out;

    float* ws = (float*)d_ws;
    _Float16* hws = (_Float16*)d_ws;
    const size_t MEGF = 1024 * 1024;      // float-unit MiB
    // Float-unit layout (lifetime overlays), peak 28.5 MEGF (unchanged):
    //   phase A: Km 0-4, Kc 4-8, Qm 8-8.5, Qc 8.5-9, e_mono 9-13,
    //            [fp16: Wt5 13-13.625 | K16 13.75-15.75 | Q16 15.75-16],
    //            V 16-20, e_chunk 20-24
    //   phase B: pcp=e_mono in-place; invcp 0-4 (over dead Km)
    //   phase C: beta 0-16 (over all dead phase-A/B temporaries),
    //            alpha 24-28, cv 28-28.5
    //   phase D: Wt_wo fp16 @ 0-0.125, cv16 fp16 @ 0.125-0.375 (dead beta)
    float* Km      = ws;
    float* Kc      = ws + 4 * MEGF;
    float* Qm      = ws + 8 * MEGF;
    float* Qc      = ws + 8 * MEGF + 512 * 1024;
    float* e_mono  = ws + 9 * MEGF;
    float* pcp     = e_mono;
    float* invcp   = ws;
    float* beta    = ws;
    float* V       = ws + 16 * MEGF;
    float* e_chunk = ws + 20 * MEGF;
    float* alpha   = ws + 24 * MEGF;
    float* cv      = ws + 28 * MEGF;
    // fp16 regions (half-unit offsets = 2x float offsets)
    _Float16* Wt5   = hws + 26 * MEGF;             // 13.0 MEGF, 5*256Kh
    _Float16* K16   = hws + 27 * MEGF + MEGF / 2;  // 13.75 MEGF, 4Mh
    _Float16* Q16   = hws + 31 * MEGF + MEGF / 2;  // 15.75 MEGF, 512Kh
    _Float16* Wt_wo = hws;                          // 0 MEGF (dead beta)
    _Float16* cv16  = hws + 262144;                 // 0.125 MEGF (dead beta)

    // 0) fp16 packing of activations + weights
    cvt_f32_f16<<<dim3(4096), 256, 0, stream>>>(key_x, K16);
    cvt_f32_f16<<<dim3(512), 256, 0, stream>>>(query_x, Q16);
    pack_weights<<<dim3(8, 8, 5), 256, 0, stream>>>(wk_m, wk_c, wv, wq_m, wq_c, Wt5);
    // 1) key-side projections (M=8192): Km, Kc, V
    mfma_proj<<<dim3(64, 12), 256, 0, stream>>>(
        K16, Wt5, bk_m, Km, bk_c, Kc, bv, V);
    // 2) query-side projections (M=1024): Qm, Qc
    mfma_proj<<<dim3(8, 8), 256, 0, stream>>>(
        Q16, Wt5 + (size_t)3 * 262144, bq_m, Qm, bq_c, Qc, bq_c, Qc);
    // 3) energies (fp32)
    energy_kernel<<<dim3(8, 4, 8), 256, 0, stream>>>(Qm, Km, mask, e_mono, r, 1);
    energy_kernel<<<dim3(8, 4, 8), 256, 0, stream>>>(Qc, Kc, mask, e_chunk, r, 0);
    // 4) monotonic alpha
    alpha_pre<<<dim3(1024), 256, 0, stream>>>(e_mono, pcp, invcp);
    alpha_scan<<<dim3(32), 64, 0, stream>>>(pcp, invcp, alpha);
    // 5) chunkwise beta
    beta_kernel<<<dim3(128, 4, 8), 256, 0, stream>>>(e_chunk, alpha, beta);
    // 6) context vectors
    context_kernel<<<dim3(2, 16, 8), 256, 0, stream>>>(beta, V, cv);
    // 7) output projection via MFMA (M=1024)
    pack_weights<<<dim3(8, 8, 1), 256, 0, stream>>>(wo, wo, wo, wo, wo, Wt_wo);
    cvt_f32_f16<<<dim3(512), 256, 0, stream>>>(cv, cv16);
    mfma_proj<<<dim3(8, 4), 256, 0, stream>>>(
        cv16, Wt_wo, bo, out, bo, out, bo, out);
}

// Round 6
// 351.317 us; speedup vs baseline: 1.9015x; 1.1049x over previous
//
#include <hip/hip_runtime.h>
#include <hip/hip_bf16.h>

// MoChA. Round 6: (1) alpha_scan 4-deep software-pipelined prefetch;
// (2) energies via fp16 MFMA — mfma_proj emits Km/Kc/Qm/Qc as fp16 directly
// (V and final out stay fp32). B=8, Q=128, K=1024, D=512, HM=HC=4, CHUNK=4.

#define NEG_INF (-3.402823466e38f)
#define EPS_MOCHA 1e-6f
#define INV_SCALE 0.04419417382415922f  // 1/sqrt(512)

typedef _Float16 half8 __attribute__((ext_vector_type(8)));
typedef _Float16 half4v __attribute__((ext_vector_type(4)));
typedef float f32x4 __attribute__((ext_vector_type(4)));

// ---------------------------------------------------------------------------
// cvt: fp32 -> fp16, vectorized x4. Grid exactly n/4/256 blocks.
// ---------------------------------------------------------------------------
__global__ __launch_bounds__(256) void cvt_f32_f16(
    const float* __restrict__ in, _Float16* __restrict__ out)
{
    const size_t i = (size_t)blockIdx.x * 256 + threadIdx.x;
    float4 v = *(const float4*)(in + i * 4);
    half4v h = {(_Float16)v.x, (_Float16)v.y, (_Float16)v.z, (_Float16)v.w};
    *(half4v*)(out + i * 4) = h;
}

// ---------------------------------------------------------------------------
// pack_weights: Wt[n][k] = (fp16) W[k][n] for up to 5 weights (grid z).
// ---------------------------------------------------------------------------
__global__ __launch_bounds__(256) void pack_weights(
    const float* __restrict__ Wa, const float* __restrict__ Wb,
    const float* __restrict__ Wc, const float* __restrict__ Wd,
    const float* __restrict__ We, _Float16* __restrict__ out)
{
    const int z = blockIdx.z;
    const float* W = (z == 0) ? Wa : (z == 1) ? Wb : (z == 2) ? Wc
                   : (z == 3) ? Wd : We;
    _Float16* O = out + (size_t)z * 512 * 512;
    const int n0 = blockIdx.x * 64, k0 = blockIdx.y * 64;
    __shared__ float T[64][65];
    const int t = threadIdx.x;
    const int rr = t >> 4, cc = (t & 15) * 4;
#pragma unroll
    for (int r = 0; r < 4; ++r) {
        int k = r * 16 + rr;
        float4 v = *(const float4*)(W + (size_t)(k0 + k) * 512 + n0 + cc);
        T[k][cc + 0] = v.x; T[k][cc + 1] = v.y;
        T[k][cc + 2] = v.z; T[k][cc + 3] = v.w;
    }
    __syncthreads();
    const int nn = t >> 2, kc = (t & 3) * 16;
    _Float16 tmp[16];
#pragma unroll
    for (int i = 0; i < 16; ++i) tmp[i] = (_Float16)T[kc + i][nn];
    _Float16* Op = O + (size_t)(n0 + nn) * 512 + k0 + kc;
    *(half8*)(Op)     = *(half8*)&tmp[0];
    *(half8*)(Op + 8) = *(half8*)&tmp[8];
}

// ---------------------------------------------------------------------------
// MFMA fragment helpers (16x16x32 f16, fp32 acc). Both operands k-contiguous
// rows of stride 512; loaded straight from global (weights L2-resident).
// ---------------------------------------------------------------------------
__device__ __forceinline__ void load_frags(
    const _Float16* Ap, const _Float16* Bp, int kk, half8 a[4], half8 b[4])
{
#pragma unroll
    for (int t = 0; t < 4; ++t) {
        a[t] = *(const half8*)(Ap + (size_t)t * 16 * 512 + kk);
        b[t] = *(const half8*)(Bp + (size_t)t * 16 * 512 + kk);
    }
}

__device__ __forceinline__ void mfma_step(half8 a[4], half8 b[4], f32x4 acc[4][4])
{
#pragma unroll
    for (int mt = 0; mt < 4; ++mt)
#pragma unroll
        for (int nt = 0; nt < 4; ++nt)
            acc[mt][nt] = __builtin_amdgcn_mfma_f32_16x16x32_f16(
                a[mt], b[nt], acc[mt][nt], 0, 0, 0);
}

// ---------------------------------------------------------------------------
// MFMA projection GEMM: C[m][n] = sum_k A16[m][k]*Wt[n][k] + bias.
// Block 256 = 2x2 waves, tile 128x128, wave 64x64 = 4x4 mfma tiles, K=512.
// f16_mask bit g: store C as fp16 (else fp32).
// Grid: (M/128, ngroups*4).
// ---------------------------------------------------------------------------
__global__ __launch_bounds__(256) void mfma_proj(
    const _Float16* __restrict__ A16, const _Float16* __restrict__ Wt_base,
    const float* __restrict__ bias0, void* __restrict__ C0,
    const float* __restrict__ bias1, void* __restrict__ C1,
    const float* __restrict__ bias2, void* __restrict__ C2,
    int f16_mask)
{
    const int tid = threadIdx.x;
    const int lane = tid & 63, wave = tid >> 6;
    const int wm = wave >> 1, wn = wave & 1;
    const int col = lane & 15, quad = lane >> 4;
    const int g = blockIdx.y >> 2, nt128 = blockIdx.y & 3;
    const _Float16* Wt = Wt_base + (size_t)g * 262144;
    const float* bias = (g == 0) ? bias0 : (g == 1) ? bias1 : bias2;
    void*        Cv   = (g == 0) ? C0    : (g == 1) ? C1    : C2;
    const int f16o = (f16_mask >> g) & 1;
    const int m0 = blockIdx.x * 128, n0 = nt128 * 128;

    const _Float16* Ap = A16 + (size_t)(m0 + wm * 64 + col) * 512 + quad * 8;
    const _Float16* Bp = Wt  + (size_t)(n0 + wn * 64 + col) * 512 + quad * 8;

    f32x4 acc[4][4];
#pragma unroll
    for (int mt = 0; mt < 4; ++mt)
#pragma unroll
        for (int nt = 0; nt < 4; ++nt) acc[mt][nt] = (f32x4)0.f;

    half8 af[4], bf[4], ag[4], bg[4];
    load_frags(Ap, Bp, 0, af, bf);
#pragma unroll
    for (int ks = 0; ks < 16; ks += 2) {
        load_frags(Ap, Bp, (ks + 1) * 32, ag, bg);
        mfma_step(af, bf, acc);
        if (ks + 2 < 16) load_frags(Ap, Bp, (ks + 2) * 32, af, bf);
        mfma_step(ag, bg, acc);
    }

    float bnt[4];
#pragma unroll
    for (int nt = 0; nt < 4; ++nt)
        bnt[nt] = bias[n0 + wn * 64 + nt * 16 + col];
#pragma unroll
    for (int mt = 0; mt < 4; ++mt) {
        const int rowb = m0 + wm * 64 + mt * 16 + quad * 4;
#pragma unroll
        for (int nt = 0; nt < 4; ++nt) {
            const int cc = n0 + wn * 64 + nt * 16 + col;
#pragma unroll
            for (int r = 0; r < 4; ++r) {
                float v = acc[mt][nt][r] + bnt[nt];
                if (f16o)
                    ((_Float16*)Cv)[(size_t)(rowb + r) * 512 + cc] = (_Float16)v;
                else
                    ((float*)Cv)[(size_t)(rowb + r) * 512 + cc] = v;
            }
        }
    }
}

// ---------------------------------------------------------------------------
// Energy via MFMA: out[b,h,q,k] = dot_128(Q16[b,q,h*128+d], K16[b,k,h*128+d])
// * INV_SCALE (+ r), masked. Block 256 = 2x2 waves; q-tile 128 x k-tile 128.
// Grid: (kt=8, h=4, b=8).
// ---------------------------------------------------------------------------
__global__ __launch_bounds__(256) void energy_mfma(
    const _Float16* __restrict__ Qp, const _Float16* __restrict__ Kp,
    const int* __restrict__ mask, float* __restrict__ out,
    const float* __restrict__ r_ptr, int use_r)
{
    const int tid = threadIdx.x;
    const int lane = tid & 63, wave = tid >> 6;
    const int wm = wave >> 1, wn = wave & 1;
    const int col = lane & 15, quad = lane >> 4;
    const int kt0 = blockIdx.x * 128;
    const int h = blockIdx.y, b = blockIdx.z;

    const _Float16* Ap = Qp + (size_t)(b * 128 + wm * 64 + col) * 512 + h * 128 + quad * 8;
    const _Float16* Bp = Kp + (size_t)(b * 1024 + kt0 + wn * 64 + col) * 512 + h * 128 + quad * 8;

    f32x4 acc[4][4];
#pragma unroll
    for (int mt = 0; mt < 4; ++mt)
#pragma unroll
        for (int nt = 0; nt < 4; ++nt) acc[mt][nt] = (f32x4)0.f;

    half8 af[4], bf[4], ag[4], bg[4];
    load_frags(Ap, Bp, 0, af, bf);
#pragma unroll
    for (int ks = 0; ks < 4; ks += 2) {
        load_frags(Ap, Bp, (ks + 1) * 32, ag, bg);
        mfma_step(af, bf, acc);
        if (ks + 2 < 4) load_frags(Ap, Bp, (ks + 2) * 32, af, bf);
        mfma_step(ag, bg, acc);
    }

    const float rv = use_r ? r_ptr[0] : 0.f;
#pragma unroll
    for (int mt = 0; mt < 4; ++mt) {
        const int qb = wm * 64 + mt * 16 + quad * 4;
#pragma unroll
        for (int nt = 0; nt < 4; ++nt) {
            const int kc = kt0 + wn * 64 + nt * 16 + col;
#pragma unroll
            for (int r = 0; r < 4; ++r) {
                const int q = qb + r;
                float v = acc[mt][nt][r] * INV_SCALE + rv;
                int mv = mask[((size_t)b * 128 + q) * 1024 + kc];
                out[(((size_t)b * 4 + h) * 128 + q) * 1024 + kc] = mv ? v : NEG_INF;
            }
        }
    }
}

// ---------------------------------------------------------------------------
// alpha_pre: parallel part of the monotonic recurrence (one wave per row).
// ---------------------------------------------------------------------------
__global__ __launch_bounds__(256) void alpha_pre(
    const float* __restrict__ e_mono, float* __restrict__ pcp,
    float* __restrict__ invcp)
{
    const int tid = threadIdx.x;
    const int lane = tid & 63;
    const int row = blockIdx.x * 4 + (tid >> 6);
    const float* E = e_mono + (size_t)row * 1024 + lane * 16;

    float e[16];
    *(float4*)&e[0]  = *(const float4*)(E);
    *(float4*)&e[4]  = *(const float4*)(E + 4);
    *(float4*)&e[8]  = *(const float4*)(E + 8);
    *(float4*)&e[12] = *(const float4*)(E + 12);

    float p[16], l[16];
#pragma unroll
    for (int i = 0; i < 16; ++i) {
        p[i] = 1.f / (1.f + expf(-e[i]));
        l[i] = logf(fmaxf(1.f - p[i], EPS_MOCHA));
    }
    float incl[16];
    incl[0] = l[0];
#pragma unroll
    for (int i = 1; i < 16; ++i) incl[i] = incl[i - 1] + l[i];
    float total = incl[15];
    float x = total;
#pragma unroll
    for (int off = 1; off < 64; off <<= 1) {
        float y = __shfl_up(x, off, 64);
        if (lane >= off) x += y;
    }
    float base = x - total;  // exclusive across lanes

    float o1[16], o2[16];
#pragma unroll
    for (int i = 0; i < 16; ++i) {
        float cl = base + (i ? incl[i - 1] : 0.f);
        float cp = expf(cl);
        o1[i] = p[i] * cp;
        o2[i] = 1.f / fmaxf(cp, EPS_MOCHA);
    }
    float* P = pcp + (size_t)row * 1024 + lane * 16;
    float* I = invcp + (size_t)row * 1024 + lane * 16;
    *(float4*)(P)      = *(float4*)&o1[0];
    *(float4*)(P + 4)  = *(float4*)&o1[4];
    *(float4*)(P + 8)  = *(float4*)&o1[8];
    *(float4*)(P + 12) = *(float4*)&o1[12];
    *(float4*)(I)      = *(float4*)&o2[0];
    *(float4*)(I + 4)  = *(float4*)&o2[4];
    *(float4*)(I + 8)  = *(float4*)&o2[8];
    *(float4*)(I + 12) = *(float4*)&o2[12];
}

// ---------------------------------------------------------------------------
// alpha_scan: sequential over q, one wave per (b,h), zero barriers. 4-deep
// software-pipelined prefetch: loads for q+4 issue at the start of step q,
// giving ~4 compute chains (>1000 cyc) to cover ~900 cyc HBM latency.
// ---------------------------------------------------------------------------
__global__ __launch_bounds__(64) void alpha_scan(
    const float* __restrict__ pcp, const float* __restrict__ invcp,
    float* __restrict__ alpha)
{
    const int lane = threadIdx.x;
    const int bh = blockIdx.x;
    const float* P = pcp + (size_t)bh * 131072 + lane * 16;
    const float* I = invcp + (size_t)bh * 131072 + lane * 16;
    float* A = alpha + (size_t)bh * 131072 + lane * 16;

    float bp[4][16], bi[4][16];
#pragma unroll
    for (int s = 0; s < 4; ++s) {
        const float* Pq = P + (size_t)s * 1024;
        const float* Iq = I + (size_t)s * 1024;
        *(float4*)&bp[s][0]  = *(const float4*)(Pq);
        *(float4*)&bp[s][4]  = *(const float4*)(Pq + 4);
        *(float4*)&bp[s][8]  = *(const float4*)(Pq + 8);
        *(float4*)&bp[s][12] = *(const float4*)(Pq + 12);
        *(float4*)&bi[s][0]  = *(const float4*)(Iq);
        *(float4*)&bi[s][4]  = *(const float4*)(Iq + 4);
        *(float4*)&bi[s][8]  = *(const float4*)(Iq + 8);
        *(float4*)&bi[s][12] = *(const float4*)(Iq + 12);
    }

    float aw[16];
#pragma unroll
    for (int i = 0; i < 16; ++i) aw[i] = 0.f;
    if (lane == 0) aw[0] = 1.f;

    for (int q4 = 0; q4 < 128; q4 += 4) {
#pragma unroll
        for (int s = 0; s < 4; ++s) {
            const int q = q4 + s;
            float pc[16], ic[16];
#pragma unroll
            for (int i = 0; i < 16; ++i) { pc[i] = bp[s][i]; ic[i] = bi[s][i]; }
            if (q + 4 < 128) {  // refill slot s for q+4 (issues before chain)
                const float* Pq = P + (size_t)(q + 4) * 1024;
                const float* Iq = I + (size_t)(q + 4) * 1024;
                *(float4*)&bp[s][0]  = *(const float4*)(Pq);
                *(float4*)&bp[s][4]  = *(const float4*)(Pq + 4);
                *(float4*)&bp[s][8]  = *(const float4*)(Pq + 8);
                *(float4*)&bp[s][12] = *(const float4*)(Pq + 12);
                *(float4*)&bi[s][0]  = *(const float4*)(Iq);
                *(float4*)&bi[s][4]  = *(const float4*)(Iq + 4);
                *(float4*)&bi[s][8]  = *(const float4*)(Iq + 8);
                *(float4*)&bi[s][12] = *(const float4*)(Iq + 12);
            }

            float incl[16];
            incl[0] = aw[0] * ic[0];
#pragma unroll
            for (int i = 1; i < 16; ++i) incl[i] = incl[i - 1] + aw[i] * ic[i];
            float total = incl[15];
            float x = total;
#pragma unroll
            for (int off = 1; off < 64; off <<= 1) {
                float y = __shfl_up(x, off, 64);
                if (lane >= off) x += y;
            }
            float base = x - total;  // exclusive across lanes
#pragma unroll
            for (int i = 0; i < 16; ++i) aw[i] = pc[i] * (base + incl[i]);

            float* Aq = A + (size_t)q * 1024;
            *(float4*)(Aq)      = *(float4*)&aw[0];
            *(float4*)(Aq + 4)  = *(float4*)&aw[4];
            *(float4*)(Aq + 8)  = *(float4*)&aw[8];
            *(float4*)(Aq + 12) = *(float4*)&aw[12];
        }
    }
}

// ---------------------------------------------------------------------------
// Beta. LDS swizzle SW(k)=k+(k>>3). Grid: (q=128, hc=4, b=8).
// ---------------------------------------------------------------------------
#define SW(k) ((k) + ((k) >> 3))

__global__ __launch_bounds__(256) void beta_kernel(
    const float* __restrict__ e_chunk, const float* __restrict__ alpha,
    float* __restrict__ beta)
{
    __shared__ float sm[SW(1023) + 1];
    __shared__ float tm[SW(1027) + 1];
    __shared__ float red[4];
    const int q = blockIdx.x, hc = blockIdx.y, b = blockIdx.z;
    const int tid = threadIdx.x;
    const int lane = tid & 63, wid = tid >> 6;
    const int k4 = tid * 4;

    const float* Erow = e_chunk + (((size_t)b * 4 + hc) * 128 + q) * 1024;
    float4 ev = *(const float4*)(Erow + k4);
    float e[4] = {ev.x, ev.y, ev.z, ev.w};

    float mx = fmaxf(fmaxf(e[0], e[1]), fmaxf(e[2], e[3]));
#pragma unroll
    for (int off = 32; off >= 1; off >>= 1)
        mx = fmaxf(mx, __shfl_xor(mx, off, 64));
    if (lane == 0) red[wid] = mx;
    if (tid < 4) tm[SW(1024 + tid)] = 0.f;
    __syncthreads();
    mx = fmaxf(fmaxf(red[0], red[1]), fmaxf(red[2], red[3]));

    float sx[4];
#pragma unroll
    for (int i = 0; i < 4; ++i) {
        sx[i] = fmaxf(expf(e[i] - mx), 1e-5f);
        sm[SW(k4 + i)] = sx[i];
    }
    __syncthreads();

    float den[4];
#pragma unroll
    for (int i = 0; i < 4; ++i) {
        int k = k4 + i;
        float d = sm[SW(k)];
        if (k >= 1) d += sm[SW(k - 1)];
        if (k >= 2) d += sm[SW(k - 2)];
        if (k >= 3) d += sm[SW(k - 3)];
        den[i] = d;
    }

    for (int hm = 0; hm < 4; ++hm) {
        const float* Arow = alpha + (((size_t)b * 4 + hm) * 128 + q) * 1024;
        float4 av = *(const float4*)(Arow + k4);
        float t[4] = {av.x / den[0], av.y / den[1], av.z / den[2], av.w / den[3]};
#pragma unroll
        for (int i = 0; i < 4; ++i) tm[SW(k4 + i)] = t[i];
        __syncthreads();
        float o[4];
#pragma unroll
        for (int i = 0; i < 4; ++i) {
            int k = k4 + i;
            float ms = tm[SW(k)] + tm[SW(k + 1)] + tm[SW(k + 2)] + tm[SW(k + 3)];
            o[i] = sx[i] * ms;
        }
        float* Brow = beta + (((size_t)b * 16 + hm * 4 + hc) * 128 + q) * 1024;
        *(float4*)(Brow + k4) = make_float4(o[0], o[1], o[2], o[3]);
        __syncthreads();
    }
}

// ---------------------------------------------------------------------------
// Context: cv[b,q,h*32+d] = sum_k beta[b,h,q,k] * V[b,k,h*32+d]
// ---------------------------------------------------------------------------
__global__ __launch_bounds__(256) void context_kernel(
    const float* __restrict__ beta, const float* __restrict__ V,
    float* __restrict__ cv)
{
    __shared__ float bS[32][64];
    __shared__ float vS[32][32];
    const int qh = blockIdx.x, h = blockIdx.y, b = blockIdx.z;
    const int tid = threadIdx.x;
    const int ty = tid >> 3, tx = tid & 7;
    const int q0 = qh * 64;

    const float* Bbase = beta + (((size_t)b * 16 + h) * 128 + q0) * 1024;
    const float* Vbase = V + (size_t)b * 1024 * 512 + h * 32;

    float acc[2][4];
#pragma unroll
    for (int i = 0; i < 2; ++i)
#pragma unroll
        for (int j = 0; j < 4; ++j) acc[i][j] = 0.f;

    for (int k0 = 0; k0 < 1024; k0 += 32) {
#pragma unroll
        for (int u = 0; u < 2; ++u) {
            int idx = tid * 2 + u;
            int row = idx >> 3, c = idx & 7;
            float4 v = *(const float4*)(Bbase + (size_t)row * 1024 + k0 + c * 4);
            bS[c * 4 + 0][row] = v.x;
            bS[c * 4 + 1][row] = v.y;
            bS[c * 4 + 2][row] = v.z;
            bS[c * 4 + 3][row] = v.w;
        }
        {
            int kk = tid >> 3, c = tid & 7;
            float4 v = *(const float4*)(Vbase + (size_t)(k0 + kk) * 512 + c * 4);
            *(float4*)&vS[kk][c * 4] = v;
        }
        __syncthreads();
#pragma unroll
        for (int kk = 0; kk < 32; ++kk) {
            float a0 = bS[kk][ty * 2], a1 = bS[kk][ty * 2 + 1];
            float bb[4];
            *(float4*)bb = *(const float4*)&vS[kk][tx * 4];
#pragma unroll
            for (int j = 0; j < 4; ++j) {
                acc[0][j] = fmaf(a0, bb[j], acc[0][j]);
                acc[1][j] = fmaf(a1, bb[j], acc[1][j]);
            }
        }
        __syncthreads();
    }
#pragma unroll
    for (int i = 0; i < 2; ++i) {
        float* Cp = cv + ((size_t)b * 128 + q0 + ty * 2 + i) * 512 + h * 32 + tx * 4;
        *(float4*)Cp = make_float4(acc[i][0], acc[i][1], acc[i][2], acc[i][3]);
    }
}

// ---------------------------------------------------------------------------
extern "C" void kernel_launch(void* const* d_in, const int* in_sizes, int n_in,
                              void* d_out, int out_size, void* d_ws, size_t ws_size,
                              hipStream_t stream)
{
    const float* key_x   = (const float*)d_in[0];
    const float* query_x = (const float*)d_in[1];
    const int*   mask    = (const int*)d_in[2];
    const float* wk_m = (const float*)d_in[3];
    const float* bk_m = (const float*)d_in[4];
    const float* wq_m = (const float*)d_in[5];
    const float* bq_m = (const float*)d_in[6];
    const float* r    = (const float*)d_in[7];
    const float* wk_c = (const float*)d_in[8];
    const float* bk_c = (const float*)d_in[9];
    const float* wq_c = (const float*)d_in[10];
    const float* bq_c = (const float*)d_in[11];
    const float* wv   = (const float*)d_in[12];
    const float* bv   = (const float*)d_in[13];
    const float* wo   = (const float*)d_in[14];
    const float* bo   = (const float*)d_in[15];
    float* out = (float*)d_out;

    float* ws = (float*)d_ws;
    _Float16* hws = (_Float16*)d_ws;
    const size_t MEGF = 1024 * 1024;
    // Float-unit layout (fp16 offsets are 2x):
    //  phase A: K16 f[0,2), Q16 f[2,2.25), Wt5 f[2.5,3.125),
    //           Km16 f[4,6), Kc16 f[6,8), Qm16 f[8,8.25), Qc16 f[8.5,8.75),
    //           e_mono f[9,13), V f[16,20), e_chunk f[20,24)
    //  phase B: pcp=e_mono in-place; invcp f[0,4) (K16/Q16/Wt5 dead)
    //  phase C: beta f[0,16) (all above dead), alpha f[24,28), cv f[28,28.5)
    //  phase D: Wt_wo h[0,256K), cv16 h[256K,768K) over dead beta.
    _Float16* K16   = hws;                          // h 0
    _Float16* Q16   = hws + 4 * MEGF;               // f 2
    _Float16* Wt5   = hws + 5 * MEGF;               // f 2.5
    _Float16* Km16  = hws + 8 * MEGF;               // f 4
    _Float16* Kc16  = hws + 12 * MEGF;              // f 6
    _Float16* Qm16  = hws + 16 * MEGF;              // f 8
    _Float16* Qc16  = hws + 17 * MEGF;              // f 8.5
    float* e_mono  = ws + 9 * MEGF;
    float* pcp     = e_mono;
    float* invcp   = ws;
    float* beta    = ws;
    float* V       = ws + 16 * MEGF;
    float* e_chunk = ws + 20 * MEGF;
    float* alpha   = ws + 24 * MEGF;
    float* cv      = ws + 28 * MEGF;
    _Float16* Wt_wo = hws;                          // phase D
    _Float16* cv16  = hws + 262144;

    // 0) fp16 packing
    cvt_f32_f16<<<dim3(4096), 256, 0, stream>>>(key_x, K16);
    cvt_f32_f16<<<dim3(512), 256, 0, stream>>>(query_x, Q16);
    pack_weights<<<dim3(8, 8, 5), 256, 0, stream>>>(wk_m, wk_c, wv, wq_m, wq_c, Wt5);
    // 1) key-side projections (M=8192): Km16 (f16), Kc16 (f16), V (f32)
    mfma_proj<<<dim3(64, 12), 256, 0, stream>>>(
        K16, Wt5, bk_m, Km16, bk_c, Kc16, bv, V, 0b011);
    // 2) query-side projections (M=1024): Qm16, Qc16 (f16)
    mfma_proj<<<dim3(8, 8), 256, 0, stream>>>(
        Q16, Wt5 + (size_t)3 * 262144, bq_m, Qm16, bq_c, Qc16, bq_c, Qc16, 0b011);
    // 3) energies via MFMA
    energy_mfma<<<dim3(8, 4, 8), 256, 0, stream>>>(Qm16, Km16, mask, e_mono, r, 1);
    energy_mfma<<<dim3(8, 4, 8), 256, 0, stream>>>(Qc16, Kc16, mask, e_chunk, r, 0);
    // 4) monotonic alpha
    alpha_pre<<<dim3(1024), 256, 0, stream>>>(e_mono, pcp, invcp);
    alpha_scan<<<dim3(32), 64, 0, stream>>>(pcp, invcp, alpha);
    // 5) chunkwise beta
    beta_kernel<<<dim3(128, 4, 8), 256, 0, stream>>>(e_chunk, alpha, beta);
    // 6) context vectors
    context_kernel<<<dim3(2, 16, 8), 256, 0, stream>>>(beta, V, cv);
    // 7) output projection via MFMA (M=1024, fp32 out)
    pack_weights<<<dim3(8, 8, 1), 256, 0, stream>>>(wo, wo, wo, wo, wo, Wt_wo);
    cvt_f32_f16<<<dim3(512), 256, 0, stream>>>(cv, cv16);
    mfma_proj<<<dim3(8, 4), 256, 0, stream>>>(
        cv16, Wt_wo, bo, out, bo, out, bo, out, 0b000);
}